// Round 10
// baseline (448.949 us; speedup 1.0000x reference)
//
#include <hip/hip_runtime.h>
#include <hip/hip_bf16.h>

#define NN 100000
#define NE 1600000
#define NG 512
#define NC 10
#define NBINS 196         // 512 dst-nodes per bin
#define BINCAP 10240      // per-bin edge cap (mean 8192, ~22 sigma)
#define EPB 8192          // edges per binp1 block

typedef __attribute__((ext_vector_type(8))) short bf16x8;
typedef __attribute__((ext_vector_type(4))) float f32x4;
typedef int int4a __attribute__((ext_vector_type(4), aligned(4)));

__device__ __forceinline__ float bflo(unsigned u) { return __uint_as_float(u << 16); }
__device__ __forceinline__ float bfhi(unsigned u) { return __uint_as_float(u & 0xffff0000u); }
__device__ __forceinline__ unsigned short f2bf(float f) {
  unsigned u = __float_as_uint(f);
  unsigned r = u + 0x7fffu + ((u >> 16) & 1u);
  return (unsigned short)(r >> 16);
}

// ---------------- binned CSR build: 512-node bins, 4B records (src<<9|local) ----------------

// pass 1: bin-group edges in LDS, burst-write packed records into per-bin stage segments
__global__ __launch_bounds__(256) void k_binp1(const int* __restrict__ src, const int* __restrict__ dst,
                                               int* __restrict__ binCursor, unsigned* __restrict__ stage) {
  __shared__ unsigned srec[EPB];          // 32 KB
  __shared__ unsigned char sbin[EPB];     // 8 KB
  __shared__ int cnt[NBINS], pre[NBINS], base[NBINS], lcur[NBINS];
  __shared__ int tmp[256];
  int t = threadIdx.x;
  if (t < NBINS) { cnt[t] = 0; lcur[t] = 0; }
  __syncthreads();
  int e0 = blockIdx.x * EPB;
  unsigned myrec[32];
  short mybin[32];
#pragma unroll
  for (int i = 0; i < 32; ++i) {
    int e = e0 + i * 256 + t;
    if (e < NE) {
      int s = src[e], d = dst[e];
      int b = d >> 9;
      mybin[i] = (short)b;
      myrec[i] = ((unsigned)s << 9) | (unsigned)(d & 511);
      atomicAdd(&cnt[b], 1);
    } else mybin[i] = -1;
  }
  __syncthreads();
  // exclusive scan cnt[196] -> pre
  int c0 = (t < NBINS) ? cnt[t] : 0;
  tmp[t] = c0;
  __syncthreads();
  for (int o = 1; o < 256; o <<= 1) { int v = (t >= o) ? tmp[t - o] : 0; __syncthreads(); tmp[t] += v; __syncthreads(); }
  if (t < NBINS) pre[t] = tmp[t] - c0;
  __syncthreads();
  if (t < NBINS && c0 > 0) base[t] = atomicAdd(&binCursor[t], c0);
  __syncthreads();
#pragma unroll
  for (int i = 0; i < 32; ++i) {
    int b = mybin[i];
    if (b >= 0) {
      int r = atomicAdd(&lcur[b], 1);
      int pos = pre[b] + r;
      srec[pos] = myrec[i];
      sbin[pos] = (unsigned char)b;
    }
  }
  __syncthreads();
  int total = NE - e0; if (total > EPB) total = EPB;
  for (int sidx = t; sidx < total; sidx += 256) {
    int b = sbin[sidx];
    stage[base[b] + (sidx - pre[b])] = srec[sidx];
  }
}

// pass 2: per bin: deg histogram -> offs/deg/dinv; scatter per-node lists
__global__ __launch_bounds__(256) void k_binp2(const unsigned* __restrict__ stage, const int* __restrict__ binCursor,
                                               int* __restrict__ csr_src, int* __restrict__ offs,
                                               int* __restrict__ deg, float* __restrict__ dinv) {
  __shared__ int ldeg[512], loff[512], lcur[512];
  __shared__ int tmp[256];
  int b = blockIdx.x, t = threadIdx.x;
  int n0 = b << 9;
  int sbase = b * BINCAP;
  int cnt = binCursor[b] - sbase; if (cnt > BINCAP) cnt = BINCAP;
  for (int i = t; i < 512; i += 256) { ldeg[i] = 0; lcur[i] = 0; }
  __syncthreads();
  for (int j = t; j < cnt; j += 256) {
    unsigned r = stage[sbase + j];
    atomicAdd(&ldeg[r & 511], 1);
  }
  __syncthreads();
  // scan ldeg[512] (2 per thread) -> loff; emit offs/deg/dinv
  int i2 = t * 2;
  int a0 = ldeg[i2], a1 = ldeg[i2 + 1];
  int s = a0 + a1;
  tmp[t] = s;
  __syncthreads();
  for (int o = 1; o < 256; o <<= 1) { int v = (t >= o) ? tmp[t - o] : 0; __syncthreads(); tmp[t] += v; __syncthreads(); }
  int ex = tmp[t] - s;
  loff[i2] = ex;
  loff[i2 + 1] = ex + a0;
  int nd0 = n0 + i2, nd1 = n0 + i2 + 1;
  if (nd0 < NN) { offs[nd0] = sbase + ex;      deg[nd0] = a0; dinv[nd0] = rsqrtf((float)a0 + 1.0f); }
  if (nd1 < NN) { offs[nd1] = sbase + ex + a0; deg[nd1] = a1; dinv[nd1] = rsqrtf((float)a1 + 1.0f); }
  __syncthreads();
  for (int j = t; j < cnt; j += 256) {
    unsigned r = stage[sbase + j];
    int li = r & 511;
    int pos = atomicAdd(&lcur[li], 1);
    csr_src[sbase + loff[li] + pos] = (int)(r >> 9);
  }
}

// 4 weight transposes + binCursor init in one launch (grid 257)
__global__ __launch_bounds__(256) void k_wt4i(const float* __restrict__ Wa, const float* __restrict__ Wb,
                                              const float* __restrict__ Wc, const float* __restrict__ Wd,
                                              unsigned short* __restrict__ Ta, unsigned short* __restrict__ Tb,
                                              unsigned short* __restrict__ Tc, unsigned short* __restrict__ Td,
                                              int* __restrict__ binCursor) {
  if (blockIdx.x == 256) {
    int t = threadIdx.x;
    if (t < NBINS) binCursor[t] = t * BINCAP;
    return;
  }
  int w = blockIdx.x >> 6;
  const float* W = (w == 0) ? Wa : (w == 1) ? Wb : (w == 2) ? Wc : Wd;
  unsigned short* T = (w == 0) ? Ta : (w == 1) ? Tb : (w == 2) ? Tc : Td;
  int idx = (blockIdx.x & 63) * 256 + threadIdx.x;
  int k = idx >> 7, c = idx & 127;
  T[c * 128 + k] = f2bf(W[k * 128 + c]);
}

// ---------------- bf16 MFMA GEMM: Out[M,128] = (A[M,128] @ W[128,128]) [*dinv_row] ----------------
// A staged in LDS (32 KB, XOR-swizzled); W read directly from global (L1/L2-hot, 32 KB).
// 5 blocks/CU occupancy (was 2 with W in LDS).

template<int ADD_BIAS, int RELU, int SRC_F32, int SCALE_ROW>
__global__ __launch_bounds__(256) void k_gemm_mfma(const void* __restrict__ Ap,
                                                   const unsigned short* __restrict__ Wt,
                                                   const float* __restrict__ bias,
                                                   const float* __restrict__ dinv,
                                                   unsigned short* __restrict__ Out, int M) {
  __shared__ uint4 Al4[2048];  // 128 rows x 16 chunks (16B = 8 bf16) = 32 KB
  int row0 = blockIdx.x * 128;
#pragma unroll
  for (int it = 0; it < 8; ++it) {
    int idx = it * 256 + threadIdx.x;
    int r = idx >> 4, c = idx & 15;
    int gr = row0 + r;
    uint4 v = make_uint4(0, 0, 0, 0);
    if (gr < M) {
      if (SRC_F32) {
        const float4* Af = (const float4*)Ap;
        float4 f0 = Af[(size_t)gr * 32 + c * 2];
        float4 f1 = Af[(size_t)gr * 32 + c * 2 + 1];
        v.x = (unsigned)f2bf(f0.x) | ((unsigned)f2bf(f0.y) << 16);
        v.y = (unsigned)f2bf(f0.z) | ((unsigned)f2bf(f0.w) << 16);
        v.z = (unsigned)f2bf(f1.x) | ((unsigned)f2bf(f1.y) << 16);
        v.w = (unsigned)f2bf(f1.z) | ((unsigned)f2bf(f1.w) << 16);
      } else {
        v = ((const uint4*)Ap)[(size_t)gr * 16 + c];
      }
    }
    Al4[r * 16 + (c ^ (r & 15))] = v;
  }
  __syncthreads();

  int lane = threadIdx.x & 63;
  int wid = threadIdx.x >> 6;
  int wr = wid >> 1, wc = wid & 1;
  int lr = lane & 15, kb = lane >> 4;
  const uint4* W16 = (const uint4*)Wt;

  f32x4 acc[4][4] = {};
#pragma unroll
  for (int ks = 0; ks < 4; ++ks) {
    int c = ks * 4 + kb;
    bf16x8 af[4], bfr[4];
#pragma unroll
    for (int i = 0; i < 4; ++i) {
      int ar = wr * 64 + i * 16 + lr;
      af[i] = *(const bf16x8*)&Al4[ar * 16 + (c ^ lr)];
      int bc = wc * 64 + i * 16 + lr;
      bfr[i] = *(const bf16x8*)&W16[bc * 16 + c];   // global read, L1-hot (W = 32 KB)
    }
#pragma unroll
    for (int i = 0; i < 4; ++i)
#pragma unroll
      for (int n = 0; n < 4; ++n)
        acc[i][n] = __builtin_amdgcn_mfma_f32_16x16x32_bf16(af[i], bfr[n], acc[i][n], 0, 0, 0);
  }

  float bcol[4];
  if (ADD_BIAS) {
#pragma unroll
    for (int n = 0; n < 4; ++n) bcol[n] = bias[wc * 64 + n * 16 + lr];
  }
#pragma unroll
  for (int i = 0; i < 4; ++i) {
    int rbase = row0 + wr * 64 + i * 16 + kb * 4;
#pragma unroll
    for (int n = 0; n < 4; ++n) {
      int col = wc * 64 + n * 16 + lr;
#pragma unroll
      for (int j = 0; j < 4; ++j) {
        int gr = rbase + j;
        if (gr < M) {
          float v = acc[i][n][j];
          if (ADD_BIAS) v += bcol[n];
          if (RELU) v = fmaxf(v, 0.f);
          if (SCALE_ROW) v *= dinv[gr];
          Out[(size_t)gr * 128 + col] = f2bf(v);
        }
      }
    }
  }
}

// ---------------- edge aggregation: wave/node, 16 gathers in flight ----------------
// hs = (h@W) * dinv (from GEMM).  out[i] = relu( (sum_e hs[src] + hs[i]) * dinv_i + b )

__global__ __launch_bounds__(256) void k_agg(const unsigned short* __restrict__ hs,
                                             const int* __restrict__ offs, const int* __restrict__ deg,
                                             const float* __restrict__ dinv,
                                             const int* __restrict__ csr_src,
                                             const float* __restrict__ bias,
                                             unsigned short* __restrict__ out) {
  int node = blockIdx.x * 4 + (threadIdx.x >> 6);
  if (node >= NN) return;
  int l = threadIdx.x & 63;
  const unsigned* hs32 = (const unsigned*)hs;  // 64 u32 per row
  float di = dinv[node];
  unsigned v = hs32[(size_t)node * 64 + l];
  float ax = bflo(v), ay = bfhi(v);  // self term hs[i]
  int p0 = offs[node], n = deg[node];
  int p = 0;
  for (; p + 16 <= n; p += 16) {
    const int* cp = csr_src + p0 + p;
    int4a i0 = *(const int4a*)cp;
    int4a i1 = *(const int4a*)(cp + 4);
    int4a i2 = *(const int4a*)(cp + 8);
    int4a i3 = *(const int4a*)(cp + 12);
    unsigned u0  = hs32[(size_t)i0.x * 64 + l], u1  = hs32[(size_t)i0.y * 64 + l];
    unsigned u2  = hs32[(size_t)i0.z * 64 + l], u3  = hs32[(size_t)i0.w * 64 + l];
    unsigned u4  = hs32[(size_t)i1.x * 64 + l], u5  = hs32[(size_t)i1.y * 64 + l];
    unsigned u6  = hs32[(size_t)i1.z * 64 + l], u7  = hs32[(size_t)i1.w * 64 + l];
    unsigned u8  = hs32[(size_t)i2.x * 64 + l], u9  = hs32[(size_t)i2.y * 64 + l];
    unsigned u10 = hs32[(size_t)i2.z * 64 + l], u11 = hs32[(size_t)i2.w * 64 + l];
    unsigned u12 = hs32[(size_t)i3.x * 64 + l], u13 = hs32[(size_t)i3.y * 64 + l];
    unsigned u14 = hs32[(size_t)i3.z * 64 + l], u15 = hs32[(size_t)i3.w * 64 + l];
    ax += bflo(u0) + bflo(u1) + bflo(u2) + bflo(u3) + bflo(u4) + bflo(u5) + bflo(u6) + bflo(u7)
        + bflo(u8) + bflo(u9) + bflo(u10) + bflo(u11) + bflo(u12) + bflo(u13) + bflo(u14) + bflo(u15);
    ay += bfhi(u0) + bfhi(u1) + bfhi(u2) + bfhi(u3) + bfhi(u4) + bfhi(u5) + bfhi(u6) + bfhi(u7)
        + bfhi(u8) + bfhi(u9) + bfhi(u10) + bfhi(u11) + bfhi(u12) + bfhi(u13) + bfhi(u14) + bfhi(u15);
  }
  for (; p + 8 <= n; p += 8) {
    const int* cp = csr_src + p0 + p;
    int4a i0 = *(const int4a*)cp;
    int4a i1 = *(const int4a*)(cp + 4);
    unsigned u0 = hs32[(size_t)i0.x * 64 + l], u1 = hs32[(size_t)i0.y * 64 + l];
    unsigned u2 = hs32[(size_t)i0.z * 64 + l], u3 = hs32[(size_t)i0.w * 64 + l];
    unsigned u4 = hs32[(size_t)i1.x * 64 + l], u5 = hs32[(size_t)i1.y * 64 + l];
    unsigned u6 = hs32[(size_t)i1.z * 64 + l], u7 = hs32[(size_t)i1.w * 64 + l];
    ax += bflo(u0) + bflo(u1) + bflo(u2) + bflo(u3) + bflo(u4) + bflo(u5) + bflo(u6) + bflo(u7);
    ay += bfhi(u0) + bfhi(u1) + bfhi(u2) + bfhi(u3) + bfhi(u4) + bfhi(u5) + bfhi(u6) + bfhi(u7);
  }
  for (; p < n; ++p) {
    int s0 = csr_src[p0 + p];
    unsigned u0 = hs32[(size_t)s0 * 64 + l];
    ax += bflo(u0);
    ay += bfhi(u0);
  }
  float2 b2 = ((const float2*)bias)[l];
  ax = fmaxf(fmaf(ax, di, b2.x), 0.f);
  ay = fmaxf(fmaf(ay, di, b2.y), 0.f);
  ((unsigned*)out)[(size_t)node * 64 + l] = (unsigned)f2bf(ax) | ((unsigned)f2bf(ay) << 16);
}

// ---------------- pooling: 4 row-streams x 64 u32-lanes per graph ----------------

__device__ __forceinline__ int lowerb(const int* a, int n, int key) {
  int lo = 0, hi = n;
  while (lo < hi) {
    int mid = (lo + hi) >> 1;
    if (a[mid] < key) lo = mid + 1; else hi = mid;
  }
  return lo;
}

__global__ __launch_bounds__(256) void k_pool(const unsigned short* __restrict__ h, const int* __restrict__ batch,
                                              float* __restrict__ g) {
  __shared__ float sx[4][64];
  __shared__ float sy[4][64];
  int gi = blockIdx.x;
  int col = threadIdx.x & 63;
  int rp = threadIdx.x >> 6;
  int lo = lowerb(batch, NN, gi), hi = lowerb(batch, NN, gi + 1);
  const unsigned* h32 = (const unsigned*)h;
  float ax = 0.f, ay = 0.f;
  for (int i = lo + rp; i < hi; i += 4) {
    unsigned u = h32[(size_t)i * 64 + col];
    ax += bflo(u);
    ay += bfhi(u);
  }
  sx[rp][col] = ax;
  sy[rp][col] = ay;
  __syncthreads();
  if (rp == 0) {
    ax = sx[0][col] + sx[1][col] + sx[2][col] + sx[3][col];
    ay = sy[0][col] + sy[1][col] + sy[2][col] + sy[3][col];
    ((float2*)g)[gi * 64 + col] = make_float2(ax, ay);
  }
}

// small f32 GEMM for t1 = relu(g @ Wr1 + br1): M=512
__global__ __launch_bounds__(256) void k_gemm_f32(const float* __restrict__ A, const float* __restrict__ W,
                                                  const float* __restrict__ bias, float* __restrict__ Out,
                                                  int M) {
  __shared__ float4 Wl[128 * 32];
  __shared__ float4 Xl[128 * 32];
  const float4* W4 = (const float4*)W;
  for (int i = threadIdx.x; i < 4096; i += 256) Wl[i] = W4[i];
  int row0 = blockIdx.x * 128;
  const float4* A4 = (const float4*)A;
  for (int i = threadIdx.x; i < 4096; i += 256) {
    int r = i >> 5, g = i & 31;
    int gr = row0 + r;
    float4 v = make_float4(0.f, 0.f, 0.f, 0.f);
    if (gr < M) v = A4[gr * 32 + g];
    Xl[r * 32 + (g ^ ((r >> 3) & 7))] = v;
  }
  __syncthreads();

  int cg = threadIdx.x & 15;
  int rg = threadIdx.x >> 4;
  int swz = rg & 7;
  float acc[8][8] = {};
  for (int g = 0; g < 32; ++g) {
    float4 xv[8];
#pragma unroll
    for (int i = 0; i < 8; ++i) xv[i] = Xl[(rg * 8 + i) * 32 + (g ^ swz)];
#pragma unroll
    for (int kk = 0; kk < 4; ++kk) {
      float4 wa = Wl[(g * 4 + kk) * 32 + cg * 2];
      float4 wb = Wl[(g * 4 + kk) * 32 + cg * 2 + 1];
#pragma unroll
      for (int i = 0; i < 8; ++i) {
        float x = (kk == 0) ? xv[i].x : (kk == 1) ? xv[i].y : (kk == 2) ? xv[i].z : xv[i].w;
        acc[i][0] = fmaf(x, wa.x, acc[i][0]);
        acc[i][1] = fmaf(x, wa.y, acc[i][1]);
        acc[i][2] = fmaf(x, wa.z, acc[i][2]);
        acc[i][3] = fmaf(x, wa.w, acc[i][3]);
        acc[i][4] = fmaf(x, wb.x, acc[i][4]);
        acc[i][5] = fmaf(x, wb.y, acc[i][5]);
        acc[i][6] = fmaf(x, wb.z, acc[i][6]);
        acc[i][7] = fmaf(x, wb.w, acc[i][7]);
      }
    }
  }
  float4 ba = ((const float4*)bias)[cg * 2];
  float4 bb = ((const float4*)bias)[cg * 2 + 1];
#pragma unroll
  for (int i = 0; i < 8; ++i) {
    int gr = row0 + rg * 8 + i;
    if (gr < M) {
      float4 oa, ob;
      oa.x = fmaxf(acc[i][0] + ba.x, 0.f); oa.y = fmaxf(acc[i][1] + ba.y, 0.f);
      oa.z = fmaxf(acc[i][2] + ba.z, 0.f); oa.w = fmaxf(acc[i][3] + ba.w, 0.f);
      ob.x = fmaxf(acc[i][4] + bb.x, 0.f); ob.y = fmaxf(acc[i][5] + bb.y, 0.f);
      ob.z = fmaxf(acc[i][6] + bb.z, 0.f); ob.w = fmaxf(acc[i][7] + bb.w, 0.f);
      ((float4*)Out)[gr * 32 + cg * 2] = oa;
      ((float4*)Out)[gr * 32 + cg * 2 + 1] = ob;
    }
  }
}

__global__ __launch_bounds__(128) void k_cls(const float* __restrict__ t, const float* __restrict__ Wr2,
                                             const float* __restrict__ br2, float* __restrict__ out) {
  int gi = blockIdx.x;
  __shared__ float row[128];
  row[threadIdx.x] = t[gi * 128 + threadIdx.x];
  __syncthreads();
  if (threadIdx.x < NC) {
    float acc = br2[threadIdx.x];
    for (int k = 0; k < 128; ++k) acc = fmaf(row[k], Wr2[k * NC + threadIdx.x], acc);
    out[gi * NC + threadIdx.x] = acc;
  }
}

// ---------------- launch ----------------

extern "C" void kernel_launch(void* const* d_in, const int* in_sizes, int n_in,
                              void* d_out, int out_size, void* d_ws, size_t ws_size,
                              hipStream_t stream) {
  const float* x     = (const float*)d_in[0];
  const int*   src   = (const int*)d_in[1];
  const int*   dst   = (const int*)d_in[2];
  const int*   batch = (const int*)d_in[3];
  const float* W_enc = (const float*)d_in[4];
  const float* b_enc = (const float*)d_in[5];
  const float* W1 = (const float*)d_in[6],  *b1 = (const float*)d_in[7];
  const float* W2 = (const float*)d_in[8],  *b2 = (const float*)d_in[9];
  const float* W3 = (const float*)d_in[10], *b3 = (const float*)d_in[11];
  const float* Wr1 = (const float*)d_in[12], *br1 = (const float*)d_in[13];
  const float* Wr2 = (const float*)d_in[14], *br2 = (const float*)d_in[15];
  float* out = (float*)d_out;

  char* ws = (char*)d_ws;
  size_t off = 0;
  auto alloc = [&](size_t bytes) {
    void* p = ws + off;
    off = (off + bytes + 255) & ~(size_t)255;
    return p;
  };
  unsigned short* h   = (unsigned short*)alloc((size_t)NN * 128 * 2);
  unsigned short* hs  = (unsigned short*)alloc((size_t)NN * 128 * 2);
  unsigned short* WtE = (unsigned short*)alloc(128 * 128 * 2);
  unsigned short* Wt1 = (unsigned short*)alloc(128 * 128 * 2);
  unsigned short* Wt2 = (unsigned short*)alloc(128 * 128 * 2);
  unsigned short* Wt3 = (unsigned short*)alloc(128 * 128 * 2);
  int*   deg      = (int*)alloc((size_t)NN * 4);
  float* dinv     = (float*)alloc((size_t)NN * 4);
  int*   offs     = (int*)alloc((size_t)NN * 4);
  int*   binCursor= (int*)alloc(NBINS * 4);
  int*   csr_src  = (int*)alloc((size_t)NBINS * BINCAP * 4);
  unsigned* stage = (unsigned*)alloc((size_t)NBINS * BINCAP * 4);
  float* g        = (float*)alloc((size_t)NG * 128 * 4);
  float* t1       = (float*)alloc((size_t)NG * 128 * 4);

  // wt4 + binCursor init first (block 256 inits cursors), then binning
  k_wt4i<<<257, 256, 0, stream>>>(W_enc, W1, W2, W3, WtE, Wt1, Wt2, Wt3, binCursor);
  k_binp1<<<(NE + EPB - 1) / EPB, 256, 0, stream>>>(src, dst, binCursor, stage);
  k_binp2<<<NBINS, 256, 0, stream>>>(stage, binCursor, csr_src, offs, deg, dinv);

  int gM = (NN + 127) / 128;  // 782
  k_gemm_mfma<1, 0, 1, 0><<<gM, 256, 0, stream>>>(x, WtE, b_enc, nullptr, h, NN);

  const unsigned short* Wts[3] = {Wt1, Wt2, Wt3};
  const float* bs[3] = {b1, b2, b3};
  int gA = (NN + 3) / 4;  // 25000
  for (int L = 0; L < 3; ++L) {
    k_gemm_mfma<0, 0, 0, 1><<<gM, 256, 0, stream>>>(h, Wts[L], nullptr, dinv, hs, NN);
    k_agg<<<gA, 256, 0, stream>>>(hs, offs, deg, dinv, csr_src, bs[L], h);
  }

  k_pool<<<NG, 256, 0, stream>>>(h, batch, g);
  k_gemm_f32<<<(NG + 127) / 128, 256, 0, stream>>>(g, Wr1, br1, t1, NG);
  k_cls<<<NG, 128, 0, stream>>>(t1, Wr2, br2, out);
}

// Round 12
// 427.665 us; speedup vs baseline: 1.0498x; 1.0498x over previous
//
#include <hip/hip_runtime.h>
#include <hip/hip_bf16.h>

#define NN 100000
#define NE 1600000
#define NG 512
#define NC 10
#define NBINS 196         // 512 dst-nodes per bin
#define BINCAP 10240      // per-bin edge cap (mean 8192, ~22 sigma)
#define EPB 8192          // edges per binp1 block

typedef __attribute__((ext_vector_type(8))) short bf16x8;
typedef __attribute__((ext_vector_type(4))) float f32x4;
typedef int int4a __attribute__((ext_vector_type(4), aligned(4)));

__device__ __forceinline__ float bflo(unsigned u) { return __uint_as_float(u << 16); }
__device__ __forceinline__ float bfhi(unsigned u) { return __uint_as_float(u & 0xffff0000u); }
__device__ __forceinline__ unsigned short f2bf(float f) {
  unsigned u = __float_as_uint(f);
  unsigned r = u + 0x7fffu + ((u >> 16) & 1u);
  return (unsigned short)(r >> 16);
}

// ---------------- binned CSR build: 512-node bins, 4B records (src<<9|local) ----------------

__global__ __launch_bounds__(256) void k_binp1(const int* __restrict__ src, const int* __restrict__ dst,
                                               int* __restrict__ binCursor, unsigned* __restrict__ stage) {
  __shared__ unsigned srec[EPB];          // 32 KB
  __shared__ unsigned char sbin[EPB];     // 8 KB
  __shared__ int cnt[NBINS], pre[NBINS], base[NBINS], lcur[NBINS];
  __shared__ int tmp[256];
  int t = threadIdx.x;
  if (t < NBINS) { cnt[t] = 0; lcur[t] = 0; }
  __syncthreads();
  int e0 = blockIdx.x * EPB;
  unsigned myrec[32];
  short mybin[32];
#pragma unroll
  for (int i = 0; i < 32; ++i) {
    int e = e0 + i * 256 + t;
    if (e < NE) {
      int s = src[e], d = dst[e];
      int b = d >> 9;
      mybin[i] = (short)b;
      myrec[i] = ((unsigned)s << 9) | (unsigned)(d & 511);
      atomicAdd(&cnt[b], 1);
    } else mybin[i] = -1;
  }
  __syncthreads();
  int c0 = (t < NBINS) ? cnt[t] : 0;
  tmp[t] = c0;
  __syncthreads();
  for (int o = 1; o < 256; o <<= 1) { int v = (t >= o) ? tmp[t - o] : 0; __syncthreads(); tmp[t] += v; __syncthreads(); }
  if (t < NBINS) pre[t] = tmp[t] - c0;
  __syncthreads();
  if (t < NBINS && c0 > 0) base[t] = atomicAdd(&binCursor[t], c0);
  __syncthreads();
#pragma unroll
  for (int i = 0; i < 32; ++i) {
    int b = mybin[i];
    if (b >= 0) {
      int r = atomicAdd(&lcur[b], 1);
      int pos = pre[b] + r;
      srec[pos] = myrec[i];
      sbin[pos] = (unsigned char)b;
    }
  }
  __syncthreads();
  int total = NE - e0; if (total > EPB) total = EPB;
  for (int sidx = t; sidx < total; sidx += 256) {
    int b = sbin[sidx];
    stage[base[b] + (sidx - pre[b])] = srec[sidx];
  }
}

__global__ __launch_bounds__(256) void k_binp2(const unsigned* __restrict__ stage, const int* __restrict__ binCursor,
                                               int* __restrict__ csr_src, int* __restrict__ offs,
                                               int* __restrict__ deg, float* __restrict__ dinv) {
  __shared__ int ldeg[512], loff[512], lcur[512];
  __shared__ int tmp[256];
  int b = blockIdx.x, t = threadIdx.x;
  int n0 = b << 9;
  int sbase = b * BINCAP;
  int cnt = binCursor[b] - sbase; if (cnt > BINCAP) cnt = BINCAP;
  for (int i = t; i < 512; i += 256) { ldeg[i] = 0; lcur[i] = 0; }
  __syncthreads();
  for (int j = t; j < cnt; j += 256) {
    unsigned r = stage[sbase + j];
    atomicAdd(&ldeg[r & 511], 1);
  }
  __syncthreads();
  int i2 = t * 2;
  int a0 = ldeg[i2], a1 = ldeg[i2 + 1];
  int s = a0 + a1;
  tmp[t] = s;
  __syncthreads();
  for (int o = 1; o < 256; o <<= 1) { int v = (t >= o) ? tmp[t - o] : 0; __syncthreads(); tmp[t] += v; __syncthreads(); }
  int ex = tmp[t] - s;
  loff[i2] = ex;
  loff[i2 + 1] = ex + a0;
  int nd0 = n0 + i2, nd1 = n0 + i2 + 1;
  if (nd0 < NN) { offs[nd0] = sbase + ex;      deg[nd0] = a0; dinv[nd0] = rsqrtf((float)a0 + 1.0f); }
  if (nd1 < NN) { offs[nd1] = sbase + ex + a0; deg[nd1] = a1; dinv[nd1] = rsqrtf((float)a1 + 1.0f); }
  __syncthreads();
  for (int j = t; j < cnt; j += 256) {
    unsigned r = stage[sbase + j];
    int li = r & 511;
    int pos = atomicAdd(&lcur[li], 1);
    csr_src[sbase + loff[li] + pos] = (int)(r >> 9);
  }
}

// 4 weight transposes + binCursor init in one launch (grid 257)
__global__ __launch_bounds__(256) void k_wt4i(const float* __restrict__ Wa, const float* __restrict__ Wb,
                                              const float* __restrict__ Wc, const float* __restrict__ Wd,
                                              unsigned short* __restrict__ Ta, unsigned short* __restrict__ Tb,
                                              unsigned short* __restrict__ Tc, unsigned short* __restrict__ Td,
                                              int* __restrict__ binCursor) {
  if (blockIdx.x == 256) {
    int t = threadIdx.x;
    if (t < NBINS) binCursor[t] = t * BINCAP;
    return;
  }
  int w = blockIdx.x >> 6;
  const float* W = (w == 0) ? Wa : (w == 1) ? Wb : (w == 2) ? Wc : Wd;
  unsigned short* T = (w == 0) ? Ta : (w == 1) ? Tb : (w == 2) ? Tc : Td;
  int idx = (blockIdx.x & 63) * 256 + threadIdx.x;
  int k = idx >> 7, c = idx & 127;
  T[c * 128 + k] = f2bf(W[k * 128 + c]);
}

// ---------------- bf16 MFMA GEMM: Out[M,128] = (A[M,128] @ W[128,128]) [*dinv_row] ----------------
// A + Wt staged in LDS (64 KB, XOR-swizzled for conflict-free ds_read_b128).
// Fast path: global_load_lds width=16 with PRE-SWIZZLED per-lane global source + linear LDS dest
// (rule #21: source permutation == read permutation). Fallback: VGPR round-trip (f32 src / edge tile).

template<int ADD_BIAS, int RELU, int SRC_F32, int SCALE_ROW>
__global__ __launch_bounds__(256) void k_gemm_mfma(const void* __restrict__ Ap,
                                                   const unsigned short* __restrict__ Wt,
                                                   const float* __restrict__ bias,
                                                   const float* __restrict__ dinv,
                                                   unsigned short* __restrict__ Out, int M) {
  __shared__ uint4 Al4[2048];  // 128 rows x 16 chunks (16B = 8 bf16)
  __shared__ uint4 Wl4[2048];
  int row0 = blockIdx.x * 128;
  const uint4* W16 = (const uint4*)Wt;
  int lane = threadIdx.x & 63;
  int wid = threadIdx.x >> 6;

  if (!SRC_F32 && row0 + 128 <= M) {
    // fast staging: 8 iters x (4 rows A + 4 rows W) per wave, 16B/lane direct-to-LDS
    const uint4* A16 = (const uint4*)Ap;
    int rl = lane >> 4, cc = lane & 15;
#pragma unroll
    for (int it = 0; it < 8; ++it) {
      int rbase = it * 16 + wid * 4;          // wave-uniform row base (4 rows)
      int row = rbase + rl;
      int chunk = cc ^ (row & 15);            // pre-swizzled source chunk
      __builtin_amdgcn_global_load_lds(
          (const __attribute__((address_space(1))) void*)(A16 + (size_t)(row0 + row) * 16 + chunk),
          (__attribute__((address_space(3))) void*)&Al4[rbase * 16], 16, 0, 0);
      __builtin_amdgcn_global_load_lds(
          (const __attribute__((address_space(1))) void*)(W16 + (size_t)row * 16 + chunk),
          (__attribute__((address_space(3))) void*)&Wl4[rbase * 16], 16, 0, 0);
    }
  } else {
#pragma unroll
    for (int it = 0; it < 8; ++it) {
      int idx = it * 256 + threadIdx.x;
      int r = idx >> 4, c = idx & 15;
      int gr = row0 + r;
      uint4 v = make_uint4(0, 0, 0, 0);
      if (gr < M) {
        if (SRC_F32) {
          const float4* Af = (const float4*)Ap;
          float4 f0 = Af[(size_t)gr * 32 + c * 2];
          float4 f1 = Af[(size_t)gr * 32 + c * 2 + 1];
          v.x = (unsigned)f2bf(f0.x) | ((unsigned)f2bf(f0.y) << 16);
          v.y = (unsigned)f2bf(f0.z) | ((unsigned)f2bf(f0.w) << 16);
          v.z = (unsigned)f2bf(f1.x) | ((unsigned)f2bf(f1.y) << 16);
          v.w = (unsigned)f2bf(f1.z) | ((unsigned)f2bf(f1.w) << 16);
        } else {
          v = ((const uint4*)Ap)[(size_t)gr * 16 + c];
        }
      }
      Al4[r * 16 + (c ^ (r & 15))] = v;
      Wl4[r * 16 + (c ^ (r & 15))] = W16[idx];
    }
  }
  __syncthreads();

  int wr = wid >> 1, wc = wid & 1;
  int lr = lane & 15, kb = lane >> 4;

  f32x4 acc[4][4] = {};
#pragma unroll
  for (int ks = 0; ks < 4; ++ks) {
    int c = ks * 4 + kb;
    bf16x8 af[4], bfr[4];
#pragma unroll
    for (int i = 0; i < 4; ++i) {
      int ar = wr * 64 + i * 16 + lr;
      af[i] = *(const bf16x8*)&Al4[ar * 16 + (c ^ lr)];
      int bc = wc * 64 + i * 16 + lr;
      bfr[i] = *(const bf16x8*)&Wl4[bc * 16 + (c ^ lr)];
    }
#pragma unroll
    for (int i = 0; i < 4; ++i)
#pragma unroll
      for (int n = 0; n < 4; ++n)
        acc[i][n] = __builtin_amdgcn_mfma_f32_16x16x32_bf16(af[i], bfr[n], acc[i][n], 0, 0, 0);
  }

  float bcol[4];
  if (ADD_BIAS) {
#pragma unroll
    for (int n = 0; n < 4; ++n) bcol[n] = bias[wc * 64 + n * 16 + lr];
  }
#pragma unroll
  for (int i = 0; i < 4; ++i) {
    int rbase = row0 + wr * 64 + i * 16 + kb * 4;
#pragma unroll
    for (int n = 0; n < 4; ++n) {
      int col = wc * 64 + n * 16 + lr;
#pragma unroll
      for (int j = 0; j < 4; ++j) {
        int gr = rbase + j;
        if (gr < M) {
          float v = acc[i][n][j];
          if (ADD_BIAS) v += bcol[n];
          if (RELU) v = fmaxf(v, 0.f);
          if (SCALE_ROW) v *= dinv[gr];
          Out[(size_t)gr * 128 + col] = f2bf(v);
        }
      }
    }
  }
}

// ---------------- edge aggregation: wave/node, 16 gathers in flight ----------------
// hs = (h@W) * dinv (from GEMM).  out[i] = relu( (sum_e hs[src] + hs[i]) * dinv_i + b )

__global__ __launch_bounds__(256) void k_agg(const unsigned short* __restrict__ hs,
                                             const int* __restrict__ offs, const int* __restrict__ deg,
                                             const float* __restrict__ dinv,
                                             const int* __restrict__ csr_src,
                                             const float* __restrict__ bias,
                                             unsigned short* __restrict__ out) {
  int node = blockIdx.x * 4 + (threadIdx.x >> 6);
  if (node >= NN) return;
  int l = threadIdx.x & 63;
  const unsigned* hs32 = (const unsigned*)hs;  // 64 u32 per row
  float di = dinv[node];
  unsigned v = hs32[(size_t)node * 64 + l];
  float ax = bflo(v), ay = bfhi(v);  // self term hs[i]
  int p0 = offs[node], n = deg[node];
  int p = 0;
  for (; p + 16 <= n; p += 16) {
    const int* cp = csr_src + p0 + p;
    int4a i0 = *(const int4a*)cp;
    int4a i1 = *(const int4a*)(cp + 4);
    int4a i2 = *(const int4a*)(cp + 8);
    int4a i3 = *(const int4a*)(cp + 12);
    unsigned u0  = hs32[(size_t)i0.x * 64 + l], u1  = hs32[(size_t)i0.y * 64 + l];
    unsigned u2  = hs32[(size_t)i0.z * 64 + l], u3  = hs32[(size_t)i0.w * 64 + l];
    unsigned u4  = hs32[(size_t)i1.x * 64 + l], u5  = hs32[(size_t)i1.y * 64 + l];
    unsigned u6  = hs32[(size_t)i1.z * 64 + l], u7  = hs32[(size_t)i1.w * 64 + l];
    unsigned u8  = hs32[(size_t)i2.x * 64 + l], u9  = hs32[(size_t)i2.y * 64 + l];
    unsigned u10 = hs32[(size_t)i2.z * 64 + l], u11 = hs32[(size_t)i2.w * 64 + l];
    unsigned u12 = hs32[(size_t)i3.x * 64 + l], u13 = hs32[(size_t)i3.y * 64 + l];
    unsigned u14 = hs32[(size_t)i3.z * 64 + l], u15 = hs32[(size_t)i3.w * 64 + l];
    ax += bflo(u0) + bflo(u1) + bflo(u2) + bflo(u3) + bflo(u4) + bflo(u5) + bflo(u6) + bflo(u7)
        + bflo(u8) + bflo(u9) + bflo(u10) + bflo(u11) + bflo(u12) + bflo(u13) + bflo(u14) + bflo(u15);
    ay += bfhi(u0) + bfhi(u1) + bfhi(u2) + bfhi(u3) + bfhi(u4) + bfhi(u5) + bfhi(u6) + bfhi(u7)
        + bfhi(u8) + bfhi(u9) + bfhi(u10) + bfhi(u11) + bfhi(u12) + bfhi(u13) + bfhi(u14) + bfhi(u15);
  }
  for (; p + 8 <= n; p += 8) {
    const int* cp = csr_src + p0 + p;
    int4a i0 = *(const int4a*)cp;
    int4a i1 = *(const int4a*)(cp + 4);
    unsigned u0 = hs32[(size_t)i0.x * 64 + l], u1 = hs32[(size_t)i0.y * 64 + l];
    unsigned u2 = hs32[(size_t)i0.z * 64 + l], u3 = hs32[(size_t)i0.w * 64 + l];
    unsigned u4 = hs32[(size_t)i1.x * 64 + l], u5 = hs32[(size_t)i1.y * 64 + l];
    unsigned u6 = hs32[(size_t)i1.z * 64 + l], u7 = hs32[(size_t)i1.w * 64 + l];
    ax += bflo(u0) + bflo(u1) + bflo(u2) + bflo(u3) + bflo(u4) + bflo(u5) + bflo(u6) + bflo(u7);
    ay += bfhi(u0) + bfhi(u1) + bfhi(u2) + bfhi(u3) + bfhi(u4) + bfhi(u5) + bfhi(u6) + bfhi(u7);
  }
  for (; p < n; ++p) {
    int s0 = csr_src[p0 + p];
    unsigned u0 = hs32[(size_t)s0 * 64 + l];
    ax += bflo(u0);
    ay += bfhi(u0);
  }
  float2 b2 = ((const float2*)bias)[l];
  ax = fmaxf(fmaf(ax, di, b2.x), 0.f);
  ay = fmaxf(fmaf(ay, di, b2.y), 0.f);
  ((unsigned*)out)[(size_t)node * 64 + l] = (unsigned)f2bf(ax) | ((unsigned)f2bf(ay) << 16);
}

// ---------------- pooling: 4 row-streams x 64 u32-lanes per graph ----------------

__device__ __forceinline__ int lowerb(const int* a, int n, int key) {
  int lo = 0, hi = n;
  while (lo < hi) {
    int mid = (lo + hi) >> 1;
    if (a[mid] < key) lo = mid + 1; else hi = mid;
  }
  return lo;
}

__global__ __launch_bounds__(256) void k_pool(const unsigned short* __restrict__ h, const int* __restrict__ batch,
                                              float* __restrict__ g) {
  __shared__ float sx[4][64];
  __shared__ float sy[4][64];
  int gi = blockIdx.x;
  int col = threadIdx.x & 63;
  int rp = threadIdx.x >> 6;
  int lo = lowerb(batch, NN, gi), hi = lowerb(batch, NN, gi + 1);
  const unsigned* h32 = (const unsigned*)h;
  float ax = 0.f, ay = 0.f;
  for (int i = lo + rp; i < hi; i += 4) {
    unsigned u = h32[(size_t)i * 64 + col];
    ax += bflo(u);
    ay += bfhi(u);
  }
  sx[rp][col] = ax;
  sy[rp][col] = ay;
  __syncthreads();
  if (rp == 0) {
    ax = sx[0][col] + sx[1][col] + sx[2][col] + sx[3][col];
    ay = sy[0][col] + sy[1][col] + sy[2][col] + sy[3][col];
    ((float2*)g)[gi * 64 + col] = make_float2(ax, ay);
  }
}

// small f32 GEMM for t1 = relu(g @ Wr1 + br1): M=512
__global__ __launch_bounds__(256) void k_gemm_f32(const float* __restrict__ A, const float* __restrict__ W,
                                                  const float* __restrict__ bias, float* __restrict__ Out,
                                                  int M) {
  __shared__ float4 Wl[128 * 32];
  __shared__ float4 Xl[128 * 32];
  const float4* W4 = (const float4*)W;
  for (int i = threadIdx.x; i < 4096; i += 256) Wl[i] = W4[i];
  int row0 = blockIdx.x * 128;
  const float4* A4 = (const float4*)A;
  for (int i = threadIdx.x; i < 4096; i += 256) {
    int r = i >> 5, g = i & 31;
    int gr = row0 + r;
    float4 v = make_float4(0.f, 0.f, 0.f, 0.f);
    if (gr < M) v = A4[gr * 32 + g];
    Xl[r * 32 + (g ^ ((r >> 3) & 7))] = v;
  }
  __syncthreads();

  int cg = threadIdx.x & 15;
  int rg = threadIdx.x >> 4;
  int swz = rg & 7;
  float acc[8][8] = {};
  for (int g = 0; g < 32; ++g) {
    float4 xv[8];
#pragma unroll
    for (int i = 0; i < 8; ++i) xv[i] = Xl[(rg * 8 + i) * 32 + (g ^ swz)];
#pragma unroll
    for (int kk = 0; kk < 4; ++kk) {
      float4 wa = Wl[(g * 4 + kk) * 32 + cg * 2];
      float4 wb = Wl[(g * 4 + kk) * 32 + cg * 2 + 1];
#pragma unroll
      for (int i = 0; i < 8; ++i) {
        float x = (kk == 0) ? xv[i].x : (kk == 1) ? xv[i].y : (kk == 2) ? xv[i].z : xv[i].w;
        acc[i][0] = fmaf(x, wa.x, acc[i][0]);
        acc[i][1] = fmaf(x, wa.y, acc[i][1]);
        acc[i][2] = fmaf(x, wa.z, acc[i][2]);
        acc[i][3] = fmaf(x, wa.w, acc[i][3]);
        acc[i][4] = fmaf(x, wb.x, acc[i][4]);
        acc[i][5] = fmaf(x, wb.y, acc[i][5]);
        acc[i][6] = fmaf(x, wb.z, acc[i][6]);
        acc[i][7] = fmaf(x, wb.w, acc[i][7]);
      }
    }
  }
  float4 ba = ((const float4*)bias)[cg * 2];
  float4 bb = ((const float4*)bias)[cg * 2 + 1];
#pragma unroll
  for (int i = 0; i < 8; ++i) {
    int gr = row0 + rg * 8 + i;
    if (gr < M) {
      float4 oa, ob;
      oa.x = fmaxf(acc[i][0] + ba.x, 0.f); oa.y = fmaxf(acc[i][1] + ba.y, 0.f);
      oa.z = fmaxf(acc[i][2] + ba.z, 0.f); oa.w = fmaxf(acc[i][3] + ba.w, 0.f);
      ob.x = fmaxf(acc[i][4] + bb.x, 0.f); ob.y = fmaxf(acc[i][5] + bb.y, 0.f);
      ob.z = fmaxf(acc[i][6] + bb.z, 0.f); ob.w = fmaxf(acc[i][7] + bb.w, 0.f);
      ((float4*)Out)[gr * 32 + cg * 2] = oa;
      ((float4*)Out)[gr * 32 + cg * 2 + 1] = ob;
    }
  }
}

__global__ __launch_bounds__(128) void k_cls(const float* __restrict__ t, const float* __restrict__ Wr2,
                                             const float* __restrict__ br2, float* __restrict__ out) {
  int gi = blockIdx.x;
  __shared__ float row[128];
  row[threadIdx.x] = t[gi * 128 + threadIdx.x];
  __syncthreads();
  if (threadIdx.x < NC) {
    float acc = br2[threadIdx.x];
    for (int k = 0; k < 128; ++k) acc = fmaf(row[k], Wr2[k * NC + threadIdx.x], acc);
    out[gi * NC + threadIdx.x] = acc;
  }
}

// ---------------- launch ----------------

extern "C" void kernel_launch(void* const* d_in, const int* in_sizes, int n_in,
                              void* d_out, int out_size, void* d_ws, size_t ws_size,
                              hipStream_t stream) {
  const float* x     = (const float*)d_in[0];
  const int*   src   = (const int*)d_in[1];
  const int*   dst   = (const int*)d_in[2];
  const int*   batch = (const int*)d_in[3];
  const float* W_enc = (const float*)d_in[4];
  const float* b_enc = (const float*)d_in[5];
  const float* W1 = (const float*)d_in[6],  *b1 = (const float*)d_in[7];
  const float* W2 = (const float*)d_in[8],  *b2 = (const float*)d_in[9];
  const float* W3 = (const float*)d_in[10], *b3 = (const float*)d_in[11];
  const float* Wr1 = (const float*)d_in[12], *br1 = (const float*)d_in[13];
  const float* Wr2 = (const float*)d_in[14], *br2 = (const float*)d_in[15];
  float* out = (float*)d_out;

  char* ws = (char*)d_ws;
  size_t off = 0;
  auto alloc = [&](size_t bytes) {
    void* p = ws + off;
    off = (off + bytes + 255) & ~(size_t)255;
    return p;
  };
  unsigned short* h   = (unsigned short*)alloc((size_t)NN * 128 * 2);
  unsigned short* hs  = (unsigned short*)alloc((size_t)NN * 128 * 2);
  unsigned short* WtE = (unsigned short*)alloc(128 * 128 * 2);
  unsigned short* Wt1 = (unsigned short*)alloc(128 * 128 * 2);
  unsigned short* Wt2 = (unsigned short*)alloc(128 * 128 * 2);
  unsigned short* Wt3 = (unsigned short*)alloc(128 * 128 * 2);
  int*   deg      = (int*)alloc((size_t)NN * 4);
  float* dinv     = (float*)alloc((size_t)NN * 4);
  int*   offs     = (int*)alloc((size_t)NN * 4);
  int*   binCursor= (int*)alloc(NBINS * 4);
  int*   csr_src  = (int*)alloc((size_t)NBINS * BINCAP * 4);
  unsigned* stage = (unsigned*)alloc((size_t)NBINS * BINCAP * 4);
  float* g        = (float*)alloc((size_t)NG * 128 * 4);
  float* t1       = (float*)alloc((size_t)NG * 128 * 4);

  k_wt4i<<<257, 256, 0, stream>>>(W_enc, W1, W2, W3, WtE, Wt1, Wt2, Wt3, binCursor);
  k_binp1<<<(NE + EPB - 1) / EPB, 256, 0, stream>>>(src, dst, binCursor, stage);
  k_binp2<<<NBINS, 256, 0, stream>>>(stage, binCursor, csr_src, offs, deg, dinv);

  int gM = (NN + 127) / 128;  // 782
  k_gemm_mfma<1, 0, 1, 0><<<gM, 256, 0, stream>>>(x, WtE, b_enc, nullptr, h, NN);

  const unsigned short* Wts[3] = {Wt1, Wt2, Wt3};
  const float* bs[3] = {b1, b2, b3};
  int gA = (NN + 3) / 4;  // 25000
  for (int L = 0; L < 3; ++L) {
    k_gemm_mfma<0, 0, 0, 1><<<gM, 256, 0, stream>>>(h, Wts[L], nullptr, dinv, hs, NN);
    k_agg<<<gA, 256, 0, stream>>>(hs, offs, deg, dinv, csr_src, bs[L], h);
  }

  k_pool<<<NG, 256, 0, stream>>>(h, batch, g);
  k_gemm_f32<<<(NG + 127) / 128, 256, 0, stream>>>(g, Wr1, br1, t1, NG);
  k_cls<<<NG, 128, 0, stream>>>(t1, Wr2, br2, out);
}

// Round 13
// 407.775 us; speedup vs baseline: 1.1010x; 1.0488x over previous
//
#include <hip/hip_runtime.h>
#include <hip/hip_bf16.h>

#define NN 100000
#define NE 1600000
#define NG 512
#define NC 10
#define NBINS 196         // 512 dst-nodes per bin
#define BINCAP 10240      // per-bin edge cap (mean 8192, ~22 sigma)
#define EPB 8192          // edges per binp1 block

typedef __attribute__((ext_vector_type(8))) short bf16x8;
typedef __attribute__((ext_vector_type(4))) float f32x4;

__device__ __forceinline__ float bflo(unsigned u) { return __uint_as_float(u << 16); }
__device__ __forceinline__ float bfhi(unsigned u) { return __uint_as_float(u & 0xffff0000u); }
__device__ __forceinline__ unsigned short f2bf(float f) {
  unsigned u = __float_as_uint(f);
  unsigned r = u + 0x7fffu + ((u >> 16) & 1u);
  return (unsigned short)(r >> 16);
}

// ---------------- binned CSR build: 512-node bins, 4B records (src<<9|local) ----------------

__global__ __launch_bounds__(256) void k_binp1(const int* __restrict__ src, const int* __restrict__ dst,
                                               int* __restrict__ binCursor, unsigned* __restrict__ stage) {
  __shared__ unsigned srec[EPB];          // 32 KB
  __shared__ unsigned char sbin[EPB];     // 8 KB
  __shared__ int cnt[NBINS], pre[NBINS], base[NBINS], lcur[NBINS];
  __shared__ int tmp[256];
  int t = threadIdx.x;
  if (t < NBINS) { cnt[t] = 0; lcur[t] = 0; }
  __syncthreads();
  int e0 = blockIdx.x * EPB;
  unsigned myrec[32];
  short mybin[32];
#pragma unroll
  for (int i = 0; i < 32; ++i) {
    int e = e0 + i * 256 + t;
    if (e < NE) {
      int s = src[e], d = dst[e];
      int b = d >> 9;
      mybin[i] = (short)b;
      myrec[i] = ((unsigned)s << 9) | (unsigned)(d & 511);
      atomicAdd(&cnt[b], 1);
    } else mybin[i] = -1;
  }
  __syncthreads();
  int c0 = (t < NBINS) ? cnt[t] : 0;
  tmp[t] = c0;
  __syncthreads();
  for (int o = 1; o < 256; o <<= 1) { int v = (t >= o) ? tmp[t - o] : 0; __syncthreads(); tmp[t] += v; __syncthreads(); }
  if (t < NBINS) pre[t] = tmp[t] - c0;
  __syncthreads();
  if (t < NBINS && c0 > 0) base[t] = atomicAdd(&binCursor[t], c0);
  __syncthreads();
#pragma unroll
  for (int i = 0; i < 32; ++i) {
    int b = mybin[i];
    if (b >= 0) {
      int r = atomicAdd(&lcur[b], 1);
      int pos = pre[b] + r;
      srec[pos] = myrec[i];
      sbin[pos] = (unsigned char)b;
    }
  }
  __syncthreads();
  int total = NE - e0; if (total > EPB) total = EPB;
  for (int sidx = t; sidx < total; sidx += 256) {
    int b = sbin[sidx];
    stage[base[b] + (sidx - pre[b])] = srec[sidx];
  }
}

__global__ __launch_bounds__(256) void k_binp2(const unsigned* __restrict__ stage, const int* __restrict__ binCursor,
                                               int* __restrict__ csr_src, int* __restrict__ offs,
                                               int* __restrict__ deg, float* __restrict__ dinv) {
  __shared__ int ldeg[512], loff[512], lcur[512];
  __shared__ int tmp[256];
  int b = blockIdx.x, t = threadIdx.x;
  int n0 = b << 9;
  int sbase = b * BINCAP;
  int cnt = binCursor[b] - sbase; if (cnt > BINCAP) cnt = BINCAP;
  for (int i = t; i < 512; i += 256) { ldeg[i] = 0; lcur[i] = 0; }
  __syncthreads();
  for (int j = t; j < cnt; j += 256) {
    unsigned r = stage[sbase + j];
    atomicAdd(&ldeg[r & 511], 1);
  }
  __syncthreads();
  int i2 = t * 2;
  int a0 = ldeg[i2], a1 = ldeg[i2 + 1];
  int s = a0 + a1;
  tmp[t] = s;
  __syncthreads();
  for (int o = 1; o < 256; o <<= 1) { int v = (t >= o) ? tmp[t - o] : 0; __syncthreads(); tmp[t] += v; __syncthreads(); }
  int ex = tmp[t] - s;
  loff[i2] = ex;
  loff[i2 + 1] = ex + a0;
  int nd0 = n0 + i2, nd1 = n0 + i2 + 1;
  if (nd0 < NN) { offs[nd0] = sbase + ex;      deg[nd0] = a0; dinv[nd0] = rsqrtf((float)a0 + 1.0f); }
  if (nd1 < NN) { offs[nd1] = sbase + ex + a0; deg[nd1] = a1; dinv[nd1] = rsqrtf((float)a1 + 1.0f); }
  __syncthreads();
  for (int j = t; j < cnt; j += 256) {
    unsigned r = stage[sbase + j];
    int li = r & 511;
    int pos = atomicAdd(&lcur[li], 1);
    csr_src[sbase + loff[li] + pos] = (int)(r >> 9);
  }
}

// 4 weight transposes + binCursor init in one launch (grid 257)
__global__ __launch_bounds__(256) void k_wt4i(const float* __restrict__ Wa, const float* __restrict__ Wb,
                                              const float* __restrict__ Wc, const float* __restrict__ Wd,
                                              unsigned short* __restrict__ Ta, unsigned short* __restrict__ Tb,
                                              unsigned short* __restrict__ Tc, unsigned short* __restrict__ Td,
                                              int* __restrict__ binCursor) {
  if (blockIdx.x == 256) {
    int t = threadIdx.x;
    if (t < NBINS) binCursor[t] = t * BINCAP;
    return;
  }
  int w = blockIdx.x >> 6;
  const float* W = (w == 0) ? Wa : (w == 1) ? Wb : (w == 2) ? Wc : Wd;
  unsigned short* T = (w == 0) ? Ta : (w == 1) ? Tb : (w == 2) ? Tc : Td;
  int idx = (blockIdx.x & 63) * 256 + threadIdx.x;
  int k = idx >> 7, c = idx & 127;
  T[c * 128 + k] = f2bf(W[k * 128 + c]);
}

// ---------------- bf16 MFMA GEMM (r12 structure: global_load_lds fast staging) ----------------

template<int ADD_BIAS, int RELU, int SRC_F32, int SCALE_ROW>
__global__ __launch_bounds__(256) void k_gemm_mfma(const void* __restrict__ Ap,
                                                   const unsigned short* __restrict__ Wt,
                                                   const float* __restrict__ bias,
                                                   const float* __restrict__ dinv,
                                                   unsigned short* __restrict__ Out, int M) {
  __shared__ uint4 Al4[2048];  // 128 rows x 16 chunks (16B = 8 bf16)
  __shared__ uint4 Wl4[2048];
  int row0 = blockIdx.x * 128;
  const uint4* W16 = (const uint4*)Wt;
  int lane = threadIdx.x & 63;
  int wid = threadIdx.x >> 6;

  if (!SRC_F32 && row0 + 128 <= M) {
    const uint4* A16 = (const uint4*)Ap;
    int rl = lane >> 4, cc = lane & 15;
#pragma unroll
    for (int it = 0; it < 8; ++it) {
      int rbase = it * 16 + wid * 4;
      int row = rbase + rl;
      int chunk = cc ^ (row & 15);
      __builtin_amdgcn_global_load_lds(
          (const __attribute__((address_space(1))) void*)(A16 + (size_t)(row0 + row) * 16 + chunk),
          (__attribute__((address_space(3))) void*)&Al4[rbase * 16], 16, 0, 0);
      __builtin_amdgcn_global_load_lds(
          (const __attribute__((address_space(1))) void*)(W16 + (size_t)row * 16 + chunk),
          (__attribute__((address_space(3))) void*)&Wl4[rbase * 16], 16, 0, 0);
    }
  } else {
#pragma unroll
    for (int it = 0; it < 8; ++it) {
      int idx = it * 256 + threadIdx.x;
      int r = idx >> 4, c = idx & 15;
      int gr = row0 + r;
      uint4 v = make_uint4(0, 0, 0, 0);
      if (gr < M) {
        if (SRC_F32) {
          const float4* Af = (const float4*)Ap;
          float4 f0 = Af[(size_t)gr * 32 + c * 2];
          float4 f1 = Af[(size_t)gr * 32 + c * 2 + 1];
          v.x = (unsigned)f2bf(f0.x) | ((unsigned)f2bf(f0.y) << 16);
          v.y = (unsigned)f2bf(f0.z) | ((unsigned)f2bf(f0.w) << 16);
          v.z = (unsigned)f2bf(f1.x) | ((unsigned)f2bf(f1.y) << 16);
          v.w = (unsigned)f2bf(f1.z) | ((unsigned)f2bf(f1.w) << 16);
        } else {
          v = ((const uint4*)Ap)[(size_t)gr * 16 + c];
        }
      }
      Al4[r * 16 + (c ^ (r & 15))] = v;
      Wl4[r * 16 + (c ^ (r & 15))] = W16[idx];
    }
  }
  __syncthreads();

  int wr = wid >> 1, wc = wid & 1;
  int lr = lane & 15, kb = lane >> 4;

  f32x4 acc[4][4] = {};
#pragma unroll
  for (int ks = 0; ks < 4; ++ks) {
    int c = ks * 4 + kb;
    bf16x8 af[4], bfr[4];
#pragma unroll
    for (int i = 0; i < 4; ++i) {
      int ar = wr * 64 + i * 16 + lr;
      af[i] = *(const bf16x8*)&Al4[ar * 16 + (c ^ lr)];
      int bc = wc * 64 + i * 16 + lr;
      bfr[i] = *(const bf16x8*)&Wl4[bc * 16 + (c ^ lr)];
    }
#pragma unroll
    for (int i = 0; i < 4; ++i)
#pragma unroll
      for (int n = 0; n < 4; ++n)
        acc[i][n] = __builtin_amdgcn_mfma_f32_16x16x32_bf16(af[i], bfr[n], acc[i][n], 0, 0, 0);
  }

  float bcol[4];
  if (ADD_BIAS) {
#pragma unroll
    for (int n = 0; n < 4; ++n) bcol[n] = bias[wc * 64 + n * 16 + lr];
  }
#pragma unroll
  for (int i = 0; i < 4; ++i) {
    int rbase = row0 + wr * 64 + i * 16 + kb * 4;
#pragma unroll
    for (int n = 0; n < 4; ++n) {
      int col = wc * 64 + n * 16 + lr;
#pragma unroll
      for (int j = 0; j < 4; ++j) {
        int gr = rbase + j;
        if (gr < M) {
          float v = acc[i][n][j];
          if (ADD_BIAS) v += bcol[n];
          if (RELU) v = fmaxf(v, 0.f);
          if (SCALE_ROW) v *= dinv[gr];
          Out[(size_t)gr * 128 + col] = f2bf(v);
        }
      }
    }
  }
}

// ---------------- edge aggregation: quad-edge vectorized gather (16B/lane, 4 edges/wave-load) ----
// Lane layout: q = lane>>4 (edge slot in quad), li = lane&15 (uint4 col within 256B row).
// Each load instruction fetches 4 edges x 256B = 1KB. Reduce via shfl_xor(16,32).
// hs = (h@W) * dinv.  out[i] = relu( (sum_e hs[src] + hs[i]) * dinv_i + b )

__global__ __launch_bounds__(256) void k_agg(const unsigned short* __restrict__ hs,
                                             const int* __restrict__ offs, const int* __restrict__ deg,
                                             const float* __restrict__ dinv,
                                             const int* __restrict__ csr_src,
                                             const float* __restrict__ bias,
                                             unsigned short* __restrict__ out) {
  int node = blockIdx.x * 4 + (threadIdx.x >> 6);
  if (node >= NN) return;
  int l = threadIdx.x & 63;
  int q = l >> 4;       // edge slot within quad
  int li = l & 15;      // uint4 index within row (16 x 16B = 256B)
  const uint4* hs4 = (const uint4*)hs;
  float a0 = 0.f, a1 = 0.f, a2 = 0.f, a3 = 0.f, a4 = 0.f, a5 = 0.f, a6 = 0.f, a7 = 0.f;
  if (q == 0) {  // self term hs[i]
    uint4 u = hs4[(size_t)node * 16 + li];
    a0 = bflo(u.x); a1 = bfhi(u.x); a2 = bflo(u.y); a3 = bfhi(u.y);
    a4 = bflo(u.z); a5 = bfhi(u.z); a6 = bflo(u.w); a7 = bfhi(u.w);
  }
  int p0 = offs[node], n = deg[node];
  int p = 0;
  for (; p + 16 <= n; p += 16) {
    int s0 = csr_src[p0 + p + q];
    int s1 = csr_src[p0 + p + 4 + q];
    int s2 = csr_src[p0 + p + 8 + q];
    int s3 = csr_src[p0 + p + 12 + q];
    uint4 u0 = hs4[(size_t)s0 * 16 + li];
    uint4 u1 = hs4[(size_t)s1 * 16 + li];
    uint4 u2 = hs4[(size_t)s2 * 16 + li];
    uint4 u3 = hs4[(size_t)s3 * 16 + li];
    a0 += bflo(u0.x) + bflo(u1.x) + bflo(u2.x) + bflo(u3.x);
    a1 += bfhi(u0.x) + bfhi(u1.x) + bfhi(u2.x) + bfhi(u3.x);
    a2 += bflo(u0.y) + bflo(u1.y) + bflo(u2.y) + bflo(u3.y);
    a3 += bfhi(u0.y) + bfhi(u1.y) + bfhi(u2.y) + bfhi(u3.y);
    a4 += bflo(u0.z) + bflo(u1.z) + bflo(u2.z) + bflo(u3.z);
    a5 += bfhi(u0.z) + bfhi(u1.z) + bfhi(u2.z) + bfhi(u3.z);
    a6 += bflo(u0.w) + bflo(u1.w) + bflo(u2.w) + bflo(u3.w);
    a7 += bfhi(u0.w) + bfhi(u1.w) + bfhi(u2.w) + bfhi(u3.w);
  }
  for (; p + 4 <= n; p += 4) {
    int s0 = csr_src[p0 + p + q];
    uint4 u = hs4[(size_t)s0 * 16 + li];
    a0 += bflo(u.x); a1 += bfhi(u.x); a2 += bflo(u.y); a3 += bfhi(u.y);
    a4 += bflo(u.z); a5 += bfhi(u.z); a6 += bflo(u.w); a7 += bfhi(u.w);
  }
  int rem = n - p;
  if (q < rem) {
    int s0 = csr_src[p0 + p + q];
    uint4 u = hs4[(size_t)s0 * 16 + li];
    a0 += bflo(u.x); a1 += bfhi(u.x); a2 += bflo(u.y); a3 += bfhi(u.y);
    a4 += bflo(u.z); a5 += bfhi(u.z); a6 += bflo(u.w); a7 += bfhi(u.w);
  }
  // reduce across the 4 quad slots
  a0 += __shfl_xor(a0, 16); a0 += __shfl_xor(a0, 32);
  a1 += __shfl_xor(a1, 16); a1 += __shfl_xor(a1, 32);
  a2 += __shfl_xor(a2, 16); a2 += __shfl_xor(a2, 32);
  a3 += __shfl_xor(a3, 16); a3 += __shfl_xor(a3, 32);
  a4 += __shfl_xor(a4, 16); a4 += __shfl_xor(a4, 32);
  a5 += __shfl_xor(a5, 16); a5 += __shfl_xor(a5, 32);
  a6 += __shfl_xor(a6, 16); a6 += __shfl_xor(a6, 32);
  a7 += __shfl_xor(a7, 16); a7 += __shfl_xor(a7, 32);
  if (q == 0) {
    float di = dinv[node];
    float4 b0 = ((const float4*)bias)[li * 2];
    float4 b1 = ((const float4*)bias)[li * 2 + 1];
    float r0 = fmaxf(fmaf(a0, di, b0.x), 0.f);
    float r1 = fmaxf(fmaf(a1, di, b0.y), 0.f);
    float r2 = fmaxf(fmaf(a2, di, b0.z), 0.f);
    float r3 = fmaxf(fmaf(a3, di, b0.w), 0.f);
    float r4 = fmaxf(fmaf(a4, di, b1.x), 0.f);
    float r5 = fmaxf(fmaf(a5, di, b1.y), 0.f);
    float r6 = fmaxf(fmaf(a6, di, b1.z), 0.f);
    float r7 = fmaxf(fmaf(a7, di, b1.w), 0.f);
    uint4 o;
    o.x = (unsigned)f2bf(r0) | ((unsigned)f2bf(r1) << 16);
    o.y = (unsigned)f2bf(r2) | ((unsigned)f2bf(r3) << 16);
    o.z = (unsigned)f2bf(r4) | ((unsigned)f2bf(r5) << 16);
    o.w = (unsigned)f2bf(r6) | ((unsigned)f2bf(r7) << 16);
    ((uint4*)out)[(size_t)node * 16 + li] = o;
  }
}

// ---------------- pooling: 4 row-streams x 64 u32-lanes per graph ----------------

__device__ __forceinline__ int lowerb(const int* a, int n, int key) {
  int lo = 0, hi = n;
  while (lo < hi) {
    int mid = (lo + hi) >> 1;
    if (a[mid] < key) lo = mid + 1; else hi = mid;
  }
  return lo;
}

__global__ __launch_bounds__(256) void k_pool(const unsigned short* __restrict__ h, const int* __restrict__ batch,
                                              float* __restrict__ g) {
  __shared__ float sx[4][64];
  __shared__ float sy[4][64];
  int gi = blockIdx.x;
  int col = threadIdx.x & 63;
  int rp = threadIdx.x >> 6;
  int lo = lowerb(batch, NN, gi), hi = lowerb(batch, NN, gi + 1);
  const unsigned* h32 = (const unsigned*)h;
  float ax = 0.f, ay = 0.f;
  for (int i = lo + rp; i < hi; i += 4) {
    unsigned u = h32[(size_t)i * 64 + col];
    ax += bflo(u);
    ay += bfhi(u);
  }
  sx[rp][col] = ax;
  sy[rp][col] = ay;
  __syncthreads();
  if (rp == 0) {
    ax = sx[0][col] + sx[1][col] + sx[2][col] + sx[3][col];
    ay = sy[0][col] + sy[1][col] + sy[2][col] + sy[3][col];
    ((float2*)g)[gi * 64 + col] = make_float2(ax, ay);
  }
}

// small f32 GEMM for t1 = relu(g @ Wr1 + br1): M=512
__global__ __launch_bounds__(256) void k_gemm_f32(const float* __restrict__ A, const float* __restrict__ W,
                                                  const float* __restrict__ bias, float* __restrict__ Out,
                                                  int M) {
  __shared__ float4 Wl[128 * 32];
  __shared__ float4 Xl[128 * 32];
  const float4* W4 = (const float4*)W;
  for (int i = threadIdx.x; i < 4096; i += 256) Wl[i] = W4[i];
  int row0 = blockIdx.x * 128;
  const float4* A4 = (const float4*)A;
  for (int i = threadIdx.x; i < 4096; i += 256) {
    int r = i >> 5, g = i & 31;
    int gr = row0 + r;
    float4 v = make_float4(0.f, 0.f, 0.f, 0.f);
    if (gr < M) v = A4[gr * 32 + g];
    Xl[r * 32 + (g ^ ((r >> 3) & 7))] = v;
  }
  __syncthreads();

  int cg = threadIdx.x & 15;
  int rg = threadIdx.x >> 4;
  int swz = rg & 7;
  float acc[8][8] = {};
  for (int g = 0; g < 32; ++g) {
    float4 xv[8];
#pragma unroll
    for (int i = 0; i < 8; ++i) xv[i] = Xl[(rg * 8 + i) * 32 + (g ^ swz)];
#pragma unroll
    for (int kk = 0; kk < 4; ++kk) {
      float4 wa = Wl[(g * 4 + kk) * 32 + cg * 2];
      float4 wb = Wl[(g * 4 + kk) * 32 + cg * 2 + 1];
#pragma unroll
      for (int i = 0; i < 8; ++i) {
        float x = (kk == 0) ? xv[i].x : (kk == 1) ? xv[i].y : (kk == 2) ? xv[i].z : xv[i].w;
        acc[i][0] = fmaf(x, wa.x, acc[i][0]);
        acc[i][1] = fmaf(x, wa.y, acc[i][1]);
        acc[i][2] = fmaf(x, wa.z, acc[i][2]);
        acc[i][3] = fmaf(x, wa.w, acc[i][3]);
        acc[i][4] = fmaf(x, wb.x, acc[i][4]);
        acc[i][5] = fmaf(x, wb.y, acc[i][5]);
        acc[i][6] = fmaf(x, wb.z, acc[i][6]);
        acc[i][7] = fmaf(x, wb.w, acc[i][7]);
      }
    }
  }
  float4 ba = ((const float4*)bias)[cg * 2];
  float4 bb = ((const float4*)bias)[cg * 2 + 1];
#pragma unroll
  for (int i = 0; i < 8; ++i) {
    int gr = row0 + rg * 8 + i;
    if (gr < M) {
      float4 oa, ob;
      oa.x = fmaxf(acc[i][0] + ba.x, 0.f); oa.y = fmaxf(acc[i][1] + ba.y, 0.f);
      oa.z = fmaxf(acc[i][2] + ba.z, 0.f); oa.w = fmaxf(acc[i][3] + ba.w, 0.f);
      ob.x = fmaxf(acc[i][4] + bb.x, 0.f); ob.y = fmaxf(acc[i][5] + bb.y, 0.f);
      ob.z = fmaxf(acc[i][6] + bb.z, 0.f); ob.w = fmaxf(acc[i][7] + bb.w, 0.f);
      ((float4*)Out)[gr * 32 + cg * 2] = oa;
      ((float4*)Out)[gr * 32 + cg * 2 + 1] = ob;
    }
  }
}

__global__ __launch_bounds__(128) void k_cls(const float* __restrict__ t, const float* __restrict__ Wr2,
                                             const float* __restrict__ br2, float* __restrict__ out) {
  int gi = blockIdx.x;
  __shared__ float row[128];
  row[threadIdx.x] = t[gi * 128 + threadIdx.x];
  __syncthreads();
  if (threadIdx.x < NC) {
    float acc = br2[threadIdx.x];
    for (int k = 0; k < 128; ++k) acc = fmaf(row[k], Wr2[k * NC + threadIdx.x], acc);
    out[gi * NC + threadIdx.x] = acc;
  }
}

// ---------------- launch ----------------

extern "C" void kernel_launch(void* const* d_in, const int* in_sizes, int n_in,
                              void* d_out, int out_size, void* d_ws, size_t ws_size,
                              hipStream_t stream) {
  const float* x     = (const float*)d_in[0];
  const int*   src   = (const int*)d_in[1];
  const int*   dst   = (const int*)d_in[2];
  const int*   batch = (const int*)d_in[3];
  const float* W_enc = (const float*)d_in[4];
  const float* b_enc = (const float*)d_in[5];
  const float* W1 = (const float*)d_in[6],  *b1 = (const float*)d_in[7];
  const float* W2 = (const float*)d_in[8],  *b2 = (const float*)d_in[9];
  const float* W3 = (const float*)d_in[10], *b3 = (const float*)d_in[11];
  const float* Wr1 = (const float*)d_in[12], *br1 = (const float*)d_in[13];
  const float* Wr2 = (const float*)d_in[14], *br2 = (const float*)d_in[15];
  float* out = (float*)d_out;

  char* ws = (char*)d_ws;
  size_t off = 0;
  auto alloc = [&](size_t bytes) {
    void* p = ws + off;
    off = (off + bytes + 255) & ~(size_t)255;
    return p;
  };
  unsigned short* h   = (unsigned short*)alloc((size_t)NN * 128 * 2);
  unsigned short* hs  = (unsigned short*)alloc((size_t)NN * 128 * 2);
  unsigned short* WtE = (unsigned short*)alloc(128 * 128 * 2);
  unsigned short* Wt1 = (unsigned short*)alloc(128 * 128 * 2);
  unsigned short* Wt2 = (unsigned short*)alloc(128 * 128 * 2);
  unsigned short* Wt3 = (unsigned short*)alloc(128 * 128 * 2);
  int*   deg      = (int*)alloc((size_t)NN * 4);
  float* dinv     = (float*)alloc((size_t)NN * 4);
  int*   offs     = (int*)alloc((size_t)NN * 4);
  int*   binCursor= (int*)alloc(NBINS * 4);
  int*   csr_src  = (int*)alloc((size_t)NBINS * BINCAP * 4);
  unsigned* stage = (unsigned*)alloc((size_t)NBINS * BINCAP * 4);
  float* g        = (float*)alloc((size_t)NG * 128 * 4);
  float* t1       = (float*)alloc((size_t)NG * 128 * 4);

  k_wt4i<<<257, 256, 0, stream>>>(W_enc, W1, W2, W3, WtE, Wt1, Wt2, Wt3, binCursor);
  k_binp1<<<(NE + EPB - 1) / EPB, 256, 0, stream>>>(src, dst, binCursor, stage);
  k_binp2<<<NBINS, 256, 0, stream>>>(stage, binCursor, csr_src, offs, deg, dinv);

  int gM = (NN + 127) / 128;  // 782
  k_gemm_mfma<1, 0, 1, 0><<<gM, 256, 0, stream>>>(x, WtE, b_enc, nullptr, h, NN);

  const unsigned short* Wts[3] = {Wt1, Wt2, Wt3};
  const float* bs[3] = {b1, b2, b3};
  int gA = (NN + 3) / 4;  // 25000
  for (int L = 0; L < 3; ++L) {
    k_gemm_mfma<0, 0, 0, 1><<<gM, 256, 0, stream>>>(h, Wts[L], nullptr, dinv, hs, NN);
    k_agg<<<gA, 256, 0, stream>>>(hs, offs, deg, dinv, csr_src, bs[L], h);
  }

  k_pool<<<NG, 256, 0, stream>>>(h, batch, g);
  k_gemm_f32<<<(NG + 127) / 128, 256, 0, stream>>>(g, Wr1, br1, t1, NG);
  k_cls<<<NG, 128, 0, stream>>>(t1, Wr2, br2, out);
}

// Round 14
// 399.694 us; speedup vs baseline: 1.1232x; 1.0202x over previous
//
#include <hip/hip_runtime.h>
#include <hip/hip_bf16.h>

#define NN 100000
#define NE 1600000
#define NG 512
#define NC 10
#define NBINS 391         // 256 dst-nodes per bin
#define BINCAP 5120       // per-bin edge cap (mean ~4092, +16 sigma)
#define EPB 4096          // edges per binp1 block

typedef __attribute__((ext_vector_type(8))) short bf16x8;
typedef __attribute__((ext_vector_type(4))) float f32x4;

__device__ __forceinline__ float bflo(unsigned u) { return __uint_as_float(u << 16); }
__device__ __forceinline__ float bfhi(unsigned u) { return __uint_as_float(u & 0xffff0000u); }
__device__ __forceinline__ unsigned short f2bf(float f) {
  unsigned u = __float_as_uint(f);
  unsigned r = u + 0x7fffu + ((u >> 16) & 1u);
  return (unsigned short)(r >> 16);
}

// ---------------- binned CSR build: 256-node bins, 4B records (src<<8|local) ----------------

// pass 1: bin-group edges in LDS, burst-write packed records into per-bin stage segments
__global__ __launch_bounds__(256) void k_binp1(const int* __restrict__ src, const int* __restrict__ dst,
                                               int* __restrict__ binCursor, unsigned* __restrict__ stage) {
  __shared__ unsigned srec[EPB];           // 16 KB
  __shared__ unsigned short sbin[EPB];     // 8 KB
  __shared__ int cnt[NBINS], pre[NBINS], base[NBINS], lcur[NBINS];  // ~6.3 KB
  __shared__ int tmp[256];
  int t = threadIdx.x;
  for (int i = t; i < NBINS; i += 256) { cnt[i] = 0; lcur[i] = 0; }
  __syncthreads();
  int e0 = blockIdx.x * EPB;
  unsigned myrec[16];
  short mybin[16];
#pragma unroll
  for (int i = 0; i < 16; ++i) {
    int e = e0 + i * 256 + t;
    if (e < NE) {
      int s = src[e], d = dst[e];
      int b = d >> 8;
      mybin[i] = (short)b;
      myrec[i] = ((unsigned)s << 8) | (unsigned)(d & 255);
      atomicAdd(&cnt[b], 1);
    } else mybin[i] = -1;
  }
  __syncthreads();
  // exclusive scan cnt[391] -> pre (2 bins per thread)
  {
    int idx0 = t * 2;
    int c0 = (idx0 < NBINS) ? cnt[idx0] : 0;
    int c1 = (idx0 + 1 < NBINS) ? cnt[idx0 + 1] : 0;
    int s = c0 + c1;
    tmp[t] = s;
    __syncthreads();
    for (int o = 1; o < 256; o <<= 1) { int v = (t >= o) ? tmp[t - o] : 0; __syncthreads(); tmp[t] += v; __syncthreads(); }
    int ex = tmp[t] - s;
    if (idx0 < NBINS) pre[idx0] = ex;
    if (idx0 + 1 < NBINS) pre[idx0 + 1] = ex + c0;
  }
  __syncthreads();
  for (int i = t; i < NBINS; i += 256) if (cnt[i] > 0) base[i] = atomicAdd(&binCursor[i], cnt[i]);
  __syncthreads();
#pragma unroll
  for (int i = 0; i < 16; ++i) {
    int b = mybin[i];
    if (b >= 0) {
      int r = atomicAdd(&lcur[b], 1);
      int pos = pre[b] + r;
      srec[pos] = myrec[i];
      sbin[pos] = (unsigned short)b;
    }
  }
  __syncthreads();
  int total = NE - e0; if (total > EPB) total = EPB;
  for (int sidx = t; sidx < total; sidx += 256) {
    int b = sbin[sidx];
    stage[base[b] + (sidx - pre[b])] = srec[sidx];
  }
}

// pass 2: per bin (256 nodes): deg histogram -> offs/deg/dinv; scatter per-node lists
__global__ __launch_bounds__(256) void k_binp2(const unsigned* __restrict__ stage, const int* __restrict__ binCursor,
                                               int* __restrict__ csr_src, int* __restrict__ offs,
                                               int* __restrict__ deg, float* __restrict__ dinv) {
  __shared__ int ldeg[256], loff[256], lcur[256];
  __shared__ int tmp[256];
  int b = blockIdx.x, t = threadIdx.x;
  int n0 = b << 8;
  int sbase = b * BINCAP;
  int cnt = binCursor[b] - sbase; if (cnt > BINCAP) cnt = BINCAP;
  ldeg[t] = 0;
  lcur[t] = 0;
  __syncthreads();
  for (int j = t; j < cnt; j += 256) {
    unsigned r = stage[sbase + j];
    atomicAdd(&ldeg[r & 255], 1);
  }
  __syncthreads();
  int a = ldeg[t];
  tmp[t] = a;
  __syncthreads();
  for (int o = 1; o < 256; o <<= 1) { int v = (t >= o) ? tmp[t - o] : 0; __syncthreads(); tmp[t] += v; __syncthreads(); }
  int ex = tmp[t] - a;
  loff[t] = ex;
  int node = n0 + t;
  if (node < NN) {
    offs[node] = sbase + ex;
    deg[node] = a;
    dinv[node] = rsqrtf((float)a + 1.0f);
  }
  __syncthreads();
  for (int j = t; j < cnt; j += 256) {
    unsigned r = stage[sbase + j];
    int li = r & 255;
    int pos = atomicAdd(&lcur[li], 1);
    csr_src[sbase + loff[li] + pos] = (int)(r >> 8);
  }
}

// 4 weight transposes + binCursor init in one launch (grid 257)
__global__ __launch_bounds__(256) void k_wt4i(const float* __restrict__ Wa, const float* __restrict__ Wb,
                                              const float* __restrict__ Wc, const float* __restrict__ Wd,
                                              unsigned short* __restrict__ Ta, unsigned short* __restrict__ Tb,
                                              unsigned short* __restrict__ Tc, unsigned short* __restrict__ Td,
                                              int* __restrict__ binCursor) {
  if (blockIdx.x == 256) {
    for (int i = threadIdx.x; i < NBINS; i += 256) binCursor[i] = i * BINCAP;
    return;
  }
  int w = blockIdx.x >> 6;
  const float* W = (w == 0) ? Wa : (w == 1) ? Wb : (w == 2) ? Wc : Wd;
  unsigned short* T = (w == 0) ? Ta : (w == 1) ? Tb : (w == 2) ? Tc : Td;
  int idx = (blockIdx.x & 63) * 256 + threadIdx.x;
  int k = idx >> 7, c = idx & 127;
  T[c * 128 + k] = f2bf(W[k * 128 + c]);
}

// ---------------- bf16 MFMA GEMM (global_load_lds fast staging, pre-swizzled source) ----------------

template<int ADD_BIAS, int RELU, int SRC_F32, int SCALE_ROW>
__global__ __launch_bounds__(256) void k_gemm_mfma(const void* __restrict__ Ap,
                                                   const unsigned short* __restrict__ Wt,
                                                   const float* __restrict__ bias,
                                                   const float* __restrict__ dinv,
                                                   unsigned short* __restrict__ Out, int M) {
  __shared__ uint4 Al4[2048];  // 128 rows x 16 chunks (16B = 8 bf16)
  __shared__ uint4 Wl4[2048];
  int row0 = blockIdx.x * 128;
  const uint4* W16 = (const uint4*)Wt;
  int lane = threadIdx.x & 63;
  int wid = threadIdx.x >> 6;

  if (!SRC_F32 && row0 + 128 <= M) {
    const uint4* A16 = (const uint4*)Ap;
    int rl = lane >> 4, cc = lane & 15;
#pragma unroll
    for (int it = 0; it < 8; ++it) {
      int rbase = it * 16 + wid * 4;
      int row = rbase + rl;
      int chunk = cc ^ (row & 15);
      __builtin_amdgcn_global_load_lds(
          (const __attribute__((address_space(1))) void*)(A16 + (size_t)(row0 + row) * 16 + chunk),
          (__attribute__((address_space(3))) void*)&Al4[rbase * 16], 16, 0, 0);
      __builtin_amdgcn_global_load_lds(
          (const __attribute__((address_space(1))) void*)(W16 + (size_t)row * 16 + chunk),
          (__attribute__((address_space(3))) void*)&Wl4[rbase * 16], 16, 0, 0);
    }
  } else {
#pragma unroll
    for (int it = 0; it < 8; ++it) {
      int idx = it * 256 + threadIdx.x;
      int r = idx >> 4, c = idx & 15;
      int gr = row0 + r;
      uint4 v = make_uint4(0, 0, 0, 0);
      if (gr < M) {
        if (SRC_F32) {
          const float4* Af = (const float4*)Ap;
          float4 f0 = Af[(size_t)gr * 32 + c * 2];
          float4 f1 = Af[(size_t)gr * 32 + c * 2 + 1];
          v.x = (unsigned)f2bf(f0.x) | ((unsigned)f2bf(f0.y) << 16);
          v.y = (unsigned)f2bf(f0.z) | ((unsigned)f2bf(f0.w) << 16);
          v.z = (unsigned)f2bf(f1.x) | ((unsigned)f2bf(f1.y) << 16);
          v.w = (unsigned)f2bf(f1.z) | ((unsigned)f2bf(f1.w) << 16);
        } else {
          v = ((const uint4*)Ap)[(size_t)gr * 16 + c];
        }
      }
      Al4[r * 16 + (c ^ (r & 15))] = v;
      Wl4[r * 16 + (c ^ (r & 15))] = W16[idx];
    }
  }
  __syncthreads();

  int wr = wid >> 1, wc = wid & 1;
  int lr = lane & 15, kb = lane >> 4;

  f32x4 acc[4][4] = {};
#pragma unroll
  for (int ks = 0; ks < 4; ++ks) {
    int c = ks * 4 + kb;
    bf16x8 af[4], bfr[4];
#pragma unroll
    for (int i = 0; i < 4; ++i) {
      int ar = wr * 64 + i * 16 + lr;
      af[i] = *(const bf16x8*)&Al4[ar * 16 + (c ^ lr)];
      int bc = wc * 64 + i * 16 + lr;
      bfr[i] = *(const bf16x8*)&Wl4[bc * 16 + (c ^ lr)];
    }
#pragma unroll
    for (int i = 0; i < 4; ++i)
#pragma unroll
      for (int n = 0; n < 4; ++n)
        acc[i][n] = __builtin_amdgcn_mfma_f32_16x16x32_bf16(af[i], bfr[n], acc[i][n], 0, 0, 0);
  }

  float bcol[4];
  if (ADD_BIAS) {
#pragma unroll
    for (int n = 0; n < 4; ++n) bcol[n] = bias[wc * 64 + n * 16 + lr];
  }
#pragma unroll
  for (int i = 0; i < 4; ++i) {
    int rbase = row0 + wr * 64 + i * 16 + kb * 4;
#pragma unroll
    for (int n = 0; n < 4; ++n) {
      int col = wc * 64 + n * 16 + lr;
#pragma unroll
      for (int j = 0; j < 4; ++j) {
        int gr = rbase + j;
        if (gr < M) {
          float v = acc[i][n][j];
          if (ADD_BIAS) v += bcol[n];
          if (RELU) v = fmaxf(v, 0.f);
          if (SCALE_ROW) v *= dinv[gr];
          Out[(size_t)gr * 128 + col] = f2bf(v);
        }
      }
    }
  }
}

// ---------------- edge aggregation: quad-edge vectorized gather (16B/lane, 4 edges/wave-load) ----

__global__ __launch_bounds__(256) void k_agg(const unsigned short* __restrict__ hs,
                                             const int* __restrict__ offs, const int* __restrict__ deg,
                                             const float* __restrict__ dinv,
                                             const int* __restrict__ csr_src,
                                             const float* __restrict__ bias,
                                             unsigned short* __restrict__ out) {
  int node = blockIdx.x * 4 + (threadIdx.x >> 6);
  if (node >= NN) return;
  int l = threadIdx.x & 63;
  int q = l >> 4;       // edge slot within quad
  int li = l & 15;      // uint4 index within row (16 x 16B = 256B)
  const uint4* hs4 = (const uint4*)hs;
  float a0 = 0.f, a1 = 0.f, a2 = 0.f, a3 = 0.f, a4 = 0.f, a5 = 0.f, a6 = 0.f, a7 = 0.f;
  if (q == 0) {  // self term hs[i]
    uint4 u = hs4[(size_t)node * 16 + li];
    a0 = bflo(u.x); a1 = bfhi(u.x); a2 = bflo(u.y); a3 = bfhi(u.y);
    a4 = bflo(u.z); a5 = bfhi(u.z); a6 = bflo(u.w); a7 = bfhi(u.w);
  }
  int p0 = offs[node], n = deg[node];
  int p = 0;
  for (; p + 16 <= n; p += 16) {
    int s0 = csr_src[p0 + p + q];
    int s1 = csr_src[p0 + p + 4 + q];
    int s2 = csr_src[p0 + p + 8 + q];
    int s3 = csr_src[p0 + p + 12 + q];
    uint4 u0 = hs4[(size_t)s0 * 16 + li];
    uint4 u1 = hs4[(size_t)s1 * 16 + li];
    uint4 u2 = hs4[(size_t)s2 * 16 + li];
    uint4 u3 = hs4[(size_t)s3 * 16 + li];
    a0 += bflo(u0.x) + bflo(u1.x) + bflo(u2.x) + bflo(u3.x);
    a1 += bfhi(u0.x) + bfhi(u1.x) + bfhi(u2.x) + bfhi(u3.x);
    a2 += bflo(u0.y) + bflo(u1.y) + bflo(u2.y) + bflo(u3.y);
    a3 += bfhi(u0.y) + bfhi(u1.y) + bfhi(u2.y) + bfhi(u3.y);
    a4 += bflo(u0.z) + bflo(u1.z) + bflo(u2.z) + bflo(u3.z);
    a5 += bfhi(u0.z) + bfhi(u1.z) + bfhi(u2.z) + bfhi(u3.z);
    a6 += bflo(u0.w) + bflo(u1.w) + bflo(u2.w) + bflo(u3.w);
    a7 += bfhi(u0.w) + bfhi(u1.w) + bfhi(u2.w) + bfhi(u3.w);
  }
  for (; p + 4 <= n; p += 4) {
    int s0 = csr_src[p0 + p + q];
    uint4 u = hs4[(size_t)s0 * 16 + li];
    a0 += bflo(u.x); a1 += bfhi(u.x); a2 += bflo(u.y); a3 += bfhi(u.y);
    a4 += bflo(u.z); a5 += bfhi(u.z); a6 += bflo(u.w); a7 += bfhi(u.w);
  }
  int rem = n - p;
  if (q < rem) {
    int s0 = csr_src[p0 + p + q];
    uint4 u = hs4[(size_t)s0 * 16 + li];
    a0 += bflo(u.x); a1 += bfhi(u.x); a2 += bflo(u.y); a3 += bfhi(u.y);
    a4 += bflo(u.z); a5 += bfhi(u.z); a6 += bflo(u.w); a7 += bfhi(u.w);
  }
  a0 += __shfl_xor(a0, 16); a0 += __shfl_xor(a0, 32);
  a1 += __shfl_xor(a1, 16); a1 += __shfl_xor(a1, 32);
  a2 += __shfl_xor(a2, 16); a2 += __shfl_xor(a2, 32);
  a3 += __shfl_xor(a3, 16); a3 += __shfl_xor(a3, 32);
  a4 += __shfl_xor(a4, 16); a4 += __shfl_xor(a4, 32);
  a5 += __shfl_xor(a5, 16); a5 += __shfl_xor(a5, 32);
  a6 += __shfl_xor(a6, 16); a6 += __shfl_xor(a6, 32);
  a7 += __shfl_xor(a7, 16); a7 += __shfl_xor(a7, 32);
  if (q == 0) {
    float di = dinv[node];
    float4 b0 = ((const float4*)bias)[li * 2];
    float4 b1 = ((const float4*)bias)[li * 2 + 1];
    float r0 = fmaxf(fmaf(a0, di, b0.x), 0.f);
    float r1 = fmaxf(fmaf(a1, di, b0.y), 0.f);
    float r2 = fmaxf(fmaf(a2, di, b0.z), 0.f);
    float r3 = fmaxf(fmaf(a3, di, b0.w), 0.f);
    float r4 = fmaxf(fmaf(a4, di, b1.x), 0.f);
    float r5 = fmaxf(fmaf(a5, di, b1.y), 0.f);
    float r6 = fmaxf(fmaf(a6, di, b1.z), 0.f);
    float r7 = fmaxf(fmaf(a7, di, b1.w), 0.f);
    uint4 o;
    o.x = (unsigned)f2bf(r0) | ((unsigned)f2bf(r1) << 16);
    o.y = (unsigned)f2bf(r2) | ((unsigned)f2bf(r3) << 16);
    o.z = (unsigned)f2bf(r4) | ((unsigned)f2bf(r5) << 16);
    o.w = (unsigned)f2bf(r6) | ((unsigned)f2bf(r7) << 16);
    ((uint4*)out)[(size_t)node * 16 + li] = o;
  }
}

// ---------------- pooling: 4 row-streams x 64 u32-lanes per graph ----------------

__device__ __forceinline__ int lowerb(const int* a, int n, int key) {
  int lo = 0, hi = n;
  while (lo < hi) {
    int mid = (lo + hi) >> 1;
    if (a[mid] < key) lo = mid + 1; else hi = mid;
  }
  return lo;
}

__global__ __launch_bounds__(256) void k_pool(const unsigned short* __restrict__ h, const int* __restrict__ batch,
                                              float* __restrict__ g) {
  __shared__ float sx[4][64];
  __shared__ float sy[4][64];
  int gi = blockIdx.x;
  int col = threadIdx.x & 63;
  int rp = threadIdx.x >> 6;
  int lo = lowerb(batch, NN, gi), hi = lowerb(batch, NN, gi + 1);
  const unsigned* h32 = (const unsigned*)h;
  float ax = 0.f, ay = 0.f;
  for (int i = lo + rp; i < hi; i += 4) {
    unsigned u = h32[(size_t)i * 64 + col];
    ax += bflo(u);
    ay += bfhi(u);
  }
  sx[rp][col] = ax;
  sy[rp][col] = ay;
  __syncthreads();
  if (rp == 0) {
    ax = sx[0][col] + sx[1][col] + sx[2][col] + sx[3][col];
    ay = sy[0][col] + sy[1][col] + sy[2][col] + sy[3][col];
    ((float2*)g)[gi * 64 + col] = make_float2(ax, ay);
  }
}

// small f32 GEMM for t1 = relu(g @ Wr1 + br1): M=512
__global__ __launch_bounds__(256) void k_gemm_f32(const float* __restrict__ A, const float* __restrict__ W,
                                                  const float* __restrict__ bias, float* __restrict__ Out,
                                                  int M) {
  __shared__ float4 Wl[128 * 32];
  __shared__ float4 Xl[128 * 32];
  const float4* W4 = (const float4*)W;
  for (int i = threadIdx.x; i < 4096; i += 256) Wl[i] = W4[i];
  int row0 = blockIdx.x * 128;
  const float4* A4 = (const float4*)A;
  for (int i = threadIdx.x; i < 4096; i += 256) {
    int r = i >> 5, g = i & 31;
    int gr = row0 + r;
    float4 v = make_float4(0.f, 0.f, 0.f, 0.f);
    if (gr < M) v = A4[gr * 32 + g];
    Xl[r * 32 + (g ^ ((r >> 3) & 7))] = v;
  }
  __syncthreads();

  int cg = threadIdx.x & 15;
  int rg = threadIdx.x >> 4;
  int swz = rg & 7;
  float acc[8][8] = {};
  for (int g = 0; g < 32; ++g) {
    float4 xv[8];
#pragma unroll
    for (int i = 0; i < 8; ++i) xv[i] = Xl[(rg * 8 + i) * 32 + (g ^ swz)];
#pragma unroll
    for (int kk = 0; kk < 4; ++kk) {
      float4 wa = Wl[(g * 4 + kk) * 32 + cg * 2];
      float4 wb = Wl[(g * 4 + kk) * 32 + cg * 2 + 1];
#pragma unroll
      for (int i = 0; i < 8; ++i) {
        float x = (kk == 0) ? xv[i].x : (kk == 1) ? xv[i].y : (kk == 2) ? xv[i].z : xv[i].w;
        acc[i][0] = fmaf(x, wa.x, acc[i][0]);
        acc[i][1] = fmaf(x, wa.y, acc[i][1]);
        acc[i][2] = fmaf(x, wa.z, acc[i][2]);
        acc[i][3] = fmaf(x, wa.w, acc[i][3]);
        acc[i][4] = fmaf(x, wb.x, acc[i][4]);
        acc[i][5] = fmaf(x, wb.y, acc[i][5]);
        acc[i][6] = fmaf(x, wb.z, acc[i][6]);
        acc[i][7] = fmaf(x, wb.w, acc[i][7]);
      }
    }
  }
  float4 ba = ((const float4*)bias)[cg * 2];
  float4 bb = ((const float4*)bias)[cg * 2 + 1];
#pragma unroll
  for (int i = 0; i < 8; ++i) {
    int gr = row0 + rg * 8 + i;
    if (gr < M) {
      float4 oa, ob;
      oa.x = fmaxf(acc[i][0] + ba.x, 0.f); oa.y = fmaxf(acc[i][1] + ba.y, 0.f);
      oa.z = fmaxf(acc[i][2] + ba.z, 0.f); oa.w = fmaxf(acc[i][3] + ba.w, 0.f);
      ob.x = fmaxf(acc[i][4] + bb.x, 0.f); ob.y = fmaxf(acc[i][5] + bb.y, 0.f);
      ob.z = fmaxf(acc[i][6] + bb.z, 0.f); ob.w = fmaxf(acc[i][7] + bb.w, 0.f);
      ((float4*)Out)[gr * 32 + cg * 2] = oa;
      ((float4*)Out)[gr * 32 + cg * 2 + 1] = ob;
    }
  }
}

__global__ __launch_bounds__(128) void k_cls(const float* __restrict__ t, const float* __restrict__ Wr2,
                                             const float* __restrict__ br2, float* __restrict__ out) {
  int gi = blockIdx.x;
  __shared__ float row[128];
  row[threadIdx.x] = t[gi * 128 + threadIdx.x];
  __syncthreads();
  if (threadIdx.x < NC) {
    float acc = br2[threadIdx.x];
    for (int k = 0; k < 128; ++k) acc = fmaf(row[k], Wr2[k * NC + threadIdx.x], acc);
    out[gi * NC + threadIdx.x] = acc;
  }
}

// ---------------- launch ----------------

extern "C" void kernel_launch(void* const* d_in, const int* in_sizes, int n_in,
                              void* d_out, int out_size, void* d_ws, size_t ws_size,
                              hipStream_t stream) {
  const float* x     = (const float*)d_in[0];
  const int*   src   = (const int*)d_in[1];
  const int*   dst   = (const int*)d_in[2];
  const int*   batch = (const int*)d_in[3];
  const float* W_enc = (const float*)d_in[4];
  const float* b_enc = (const float*)d_in[5];
  const float* W1 = (const float*)d_in[6],  *b1 = (const float*)d_in[7];
  const float* W2 = (const float*)d_in[8],  *b2 = (const float*)d_in[9];
  const float* W3 = (const float*)d_in[10], *b3 = (const float*)d_in[11];
  const float* Wr1 = (const float*)d_in[12], *br1 = (const float*)d_in[13];
  const float* Wr2 = (const float*)d_in[14], *br2 = (const float*)d_in[15];
  float* out = (float*)d_out;

  char* ws = (char*)d_ws;
  size_t off = 0;
  auto alloc = [&](size_t bytes) {
    void* p = ws + off;
    off = (off + bytes + 255) & ~(size_t)255;
    return p;
  };
  unsigned short* h   = (unsigned short*)alloc((size_t)NN * 128 * 2);
  unsigned short* hs  = (unsigned short*)alloc((size_t)NN * 128 * 2);
  unsigned short* WtE = (unsigned short*)alloc(128 * 128 * 2);
  unsigned short* Wt1 = (unsigned short*)alloc(128 * 128 * 2);
  unsigned short* Wt2 = (unsigned short*)alloc(128 * 128 * 2);
  unsigned short* Wt3 = (unsigned short*)alloc(128 * 128 * 2);
  int*   deg      = (int*)alloc((size_t)NN * 4);
  float* dinv     = (float*)alloc((size_t)NN * 4);
  int*   offs     = (int*)alloc((size_t)NN * 4);
  int*   binCursor= (int*)alloc(NBINS * 4);
  int*   csr_src  = (int*)alloc((size_t)NBINS * BINCAP * 4);
  unsigned* stage = (unsigned*)alloc((size_t)NBINS * BINCAP * 4);
  float* g        = (float*)alloc((size_t)NG * 128 * 4);
  float* t1       = (float*)alloc((size_t)NG * 128 * 4);

  k_wt4i<<<257, 256, 0, stream>>>(W_enc, W1, W2, W3, WtE, Wt1, Wt2, Wt3, binCursor);
  k_binp1<<<(NE + EPB - 1) / EPB, 256, 0, stream>>>(src, dst, binCursor, stage);
  k_binp2<<<NBINS, 256, 0, stream>>>(stage, binCursor, csr_src, offs, deg, dinv);

  int gM = (NN + 127) / 128;  // 782
  k_gemm_mfma<1, 0, 1, 0><<<gM, 256, 0, stream>>>(x, WtE, b_enc, nullptr, h, NN);

  const unsigned short* Wts[3] = {Wt1, Wt2, Wt3};
  const float* bs[3] = {b1, b2, b3};
  int gA = (NN + 3) / 4;  // 25000
  for (int L = 0; L < 3; ++L) {
    k_gemm_mfma<0, 0, 0, 1><<<gM, 256, 0, stream>>>(h, Wts[L], nullptr, dinv, hs, NN);
    k_agg<<<gA, 256, 0, stream>>>(hs, offs, deg, dinv, csr_src, bs[L], h);
  }

  k_pool<<<NG, 256, 0, stream>>>(h, batch, g);
  k_gemm_f32<<<(NG + 127) / 128, 256, 0, stream>>>(g, Wr1, br1, t1, NG);
  k_cls<<<NG, 128, 0, stream>>>(t1, Wr2, br2, out);
}